// Round 14
// baseline (1238.519 us; speedup 1.0000x reference)
//
#include <hip/hip_runtime.h>
#include <hip/hip_bf16.h>
#include <math.h>

#define NBLK 6
#define NH 4
#define CCH 192
#define BB 2
#define SS 64
#define LL 256
#define DH 48
#define NP (BB*SS*LL)            // 32768 pixels
#define BUF ((size_t)NP*CCH)

typedef __attribute__((ext_vector_type(8))) short short8;
typedef __attribute__((ext_vector_type(4))) float float4v;

__device__ __forceinline__ unsigned short f2b(float f) {
    union { float f; unsigned int u; } v; v.f = f;
    unsigned int r = v.u + 0x7FFF + ((v.u >> 16) & 1);
    return (unsigned short)(r >> 16);
}
__device__ __forceinline__ float b2f(unsigned short u) {
    union { unsigned int u; float f; } v; v.u = ((unsigned int)u) << 16;
    return v.f;
}
__device__ __forceinline__ void async_lds16(const void* g, void* l) {
    __builtin_amdgcn_global_load_lds(
        (const __attribute__((address_space(1))) unsigned int*)g,
        (__attribute__((address_space(3))) unsigned int*)l, 16, 0, 0);
}

// ---------- weight prep: fragment-major swizzle ----------
template<int N, int K>
__global__ void swz_conv(const float* __restrict__ src, unsigned short* __restrict__ dst, int layers) {
    int s = blockIdx.x * 256 + threadIdx.x;
    if (s >= layers * N * K) return;
    int li = s / (N * K);
    int t = s - li * (N * K);
    constexpr int KC = K / 32;
    int chunk = t >> 9, c = t & 511;
    int g = chunk / KC, sk = chunk - g * KC;
    int lane = c >> 3, ko = c & 7;
    int n = g * 16 + (lane & 15), k = sk * 32 + (lane >> 4) * 8 + ko;
    dst[s] = f2b(src[(size_t)li * N * K + (size_t)n * K + k]);
}
__global__ void wqkv_swz(const float* __restrict__ wq, const float* __restrict__ wk,
                         const float* __restrict__ wv, unsigned short* __restrict__ d) {
    int s = blockIdx.x * 256 + threadIdx.x;          // 12*576*192
    int wi = s / (576 * 192);
    int t = s - wi * 576 * 192;
    int chunk = t >> 9, c = t & 511;
    int g = chunk / 6, sk = chunk - g * 6;
    int lane = c >> 3, ko = c & 7;
    int n = g * 16 + (lane & 15), k = sk * 32 + (lane >> 4) * 8 + ko;
    int sg = n / 192, row = n - sg * 192;
    const float* src = (sg == 0) ? wq : (sg == 1) ? wk : wv;
    d[s] = f2b(src[(size_t)wi * 192 * 192 + (size_t)row * 192 + k]);
}
__global__ void bqkv_concat(const float* __restrict__ bq, const float* __restrict__ bk,
                            const float* __restrict__ bv, float* __restrict__ d) {
    int idx = blockIdx.x * 256 + threadIdx.x;        // 12*576
    if (idx >= NBLK * 2 * 576) return;
    int wi = idx / 576, n = idx - (idx / 576) * 576;
    int sg = n / 192, row = n - sg * 192;
    const float* src = (sg == 0) ? bq : (sg == 1) ? bk : bv;
    d[idx] = src[wi * CCH + row];
}

__global__ void gather_kernel(const int* __restrict__ tokens, const float* __restrict__ emb,
                              unsigned short* __restrict__ Eg) {
    int idx = blockIdx.x * 256 + threadIdx.x;   // NP*64
    int p = idx >> 6, c = idx & 63;
    Eg[idx] = f2b(emb[tokens[p] * 64 + c]);
}

// rotary + first LayerNorm fused
__global__ __launch_bounds__(256) void rotary_ln_kernel(const float* __restrict__ Xt, float* __restrict__ X,
                                                        unsigned short* __restrict__ Hn,
                                                        const float* __restrict__ g, const float* __restrict__ b) {
    int wave = threadIdx.x >> 6;
    int lane = threadIdx.x & 63;
    int p = blockIdx.x * 4 + wave;
    int l = p & (LL - 1);
    const float* xp = Xt + (size_t)p * CCH;
    float v[3];
    #pragma unroll
    for (int i = 0; i < 3; ++i) {
        int c = lane + i * 64;
        int j = c % 96;
        float inv = expf((float)(2 * j) * (-9.210340371976184f / 192.0f));
        float ang = (float)l * inv;
        float part = (c < 96) ? -xp[c + 96] : xp[c - 96];
        v[i] = xp[c] * cosf(ang) + part * sinf(ang);
    }
    float s = v[0] + v[1] + v[2];
    float qq = v[0] * v[0] + v[1] * v[1] + v[2] * v[2];
    #pragma unroll
    for (int off = 32; off; off >>= 1) {
        s += __shfl_xor(s, off, 64);
        qq += __shfl_xor(qq, off, 64);
    }
    float mean = s * (1.0f / 192.0f);
    float var = qq * (1.0f / 192.0f) - mean * mean;
    float r = rsqrtf(var + 1e-5f);
    float* op = X + (size_t)p * CCH;
    unsigned short* hp = Hn + (size_t)p * CCH;
    #pragma unroll
    for (int i = 0; i < 3; ++i) {
        int c = lane + i * 64;
        op[c] = v[i];
        hp[c] = f2b((v[i] - mean) * r * g[c] + b[c]);
    }
}

// ---------------- bf16 MFMA GEMM (pre-loop only: proj, block-0 QKV) ----------------
template<int MT, int EPI>
__global__ __launch_bounds__(256, (MT == 128) ? 3 : 4)
void mm192(const unsigned short* __restrict__ A, const unsigned short* __restrict__ Wsw,
           const float* __restrict__ bias,
           unsigned short* __restrict__ O0, unsigned short* __restrict__ O1,
           unsigned short* __restrict__ O2,
           float* __restrict__ Of,
           int M, int N, int K) {
    constexpr int NI = MT / 32;
    __shared__ __align__(16) unsigned char lds[(MT == 128) ? 51200 : 28672];
    const int tid = threadIdx.x;
    const int lane = tid & 63;
    const int w = tid >> 6;
    const int wm = w >> 1, wn = w & 1;
    const int m0 = blockIdx.y * MT;
    const int g0 = blockIdx.x * 12;
    const int q = lane >> 4;
    const int q8 = q << 3;
    const int r15 = lane & 15;
    const int KC = K >> 5;

    for (int c = w; c < (MT / 16) * KC; c += 4) {
        int g = c / KC, sk = c - g * KC;
        async_lds16(A + (size_t)(m0 + g * 16 + r15) * K + sk * 32 + q8, lds + c * 1024);
    }

    float4v acc[NI][6];
    #pragma unroll
    for (int i = 0; i < NI; ++i)
        #pragma unroll
        for (int j = 0; j < 6; ++j)
            acc[i][j] = (float4v){0.f, 0.f, 0.f, 0.f};

    __syncthreads();

    for (int sk = 0; sk < KC; ++sk) {
        short8 af[NI], wf[6];
        #pragma unroll
        for (int j = 0; j < 6; ++j)
            wf[j] = *(const short8*)(Wsw + (((size_t)(g0 + wn * 6 + j) * KC + sk) << 9) + lane * 8);
        #pragma unroll
        for (int i = 0; i < NI; ++i)
            af[i] = *(const short8*)(lds + (((wm * NI + i) * KC + sk) << 10) + lane * 16);
        #pragma unroll
        for (int i = 0; i < NI; ++i)
            #pragma unroll
            for (int j = 0; j < 6; ++j)
                acc[i][j] = __builtin_amdgcn_mfma_f32_16x16x32_bf16(af[i], wf[j], acc[i][j], 0, 0, 0);
    }

    const int nb = blockIdx.x * 192 + wn * 96 + r15;
    const int mb = m0 + wm * (MT / 2) + q * 4;

    if (EPI == 0) {
        unsigned short* TB = (unsigned short*)lds;
        const int bx = blockIdx.x;
        __syncthreads();
        #pragma unroll
        for (int j = 0; j < 6; ++j) {
            float bv = bias[nb + j * 16];
            #pragma unroll
            for (int i = 0; i < NI; ++i) {
                int row = wm * (MT / 2) + i * 16 + q * 4;
                #pragma unroll
                for (int r = 0; r < 4; ++r) {
                    float v = acc[i][j][r] + bv;
                    if (bx < 2) v = (v > 0.f) ? v + 1.f : expf(v);
                    if (bx == 0) v *= 0.14433756729740643f;
                    TB[(row + r) * 200 + wn * 96 + j * 16 + r15] = f2b(v);
                }
            }
        }
        __syncthreads();
        unsigned short* dst = (bx == 0) ? O0 : (bx == 1) ? O1 : O2;
        #pragma unroll
        for (int it = 0; it < (MT * 192) / 2048; ++it) {
            int idx = (it * 256 + tid) * 8;
            int row = idx / 192, col = idx - row * 192;
            *(short8*)(dst + (size_t)(m0 + row) * 192 + col) = *(const short8*)&TB[row * 200 + col];
        }
    } else {
        #pragma unroll
        for (int j = 0; j < 6; ++j) {
            int n = nb + j * 16;
            float bv = bias[n];
            #pragma unroll
            for (int i = 0; i < NI; ++i) {
                int mrow = mb + i * 16;
                #pragma unroll
                for (int r = 0; r < 4; ++r)
                    Of[(size_t)(mrow + r) * N + n] = acc[i][j][r] + bv;
            }
        }
    }
}

// ================= fused per-pixel GEMM chains (64 rows/block, grid = NP/64) =================
// LDS (52224 B): Lo [0,25600) staging/Hreg/TB | stats [25600,26624) | Ap [27648,52224)
// A'/Hreg chunk layout: chunk (g*6+sk)*1024B, element (m=g*16+r15, k=sk*32+q*8+t).

// ---- WO + residual + LN + QKV ----
__global__ __launch_bounds__(256, 3)
void wo_qkv(const unsigned short* __restrict__ Ho,
            const unsigned short* __restrict__ WOs, const float* __restrict__ BO,
            float* __restrict__ Xres,
            const float* __restrict__ lng, const float* __restrict__ lnb,
            const unsigned short* __restrict__ QKVs, const float* __restrict__ bqkv,
            unsigned short* __restrict__ Qb, unsigned short* __restrict__ Kb,
            unsigned short* __restrict__ Vb) {
    __shared__ __align__(16) unsigned char lds[52224];
    unsigned char* Lo = lds;
    float* lsum = (float*)(lds + 25600);
    float* lsq  = lsum + 128;
    unsigned char* Ap = lds + 27648;
    const int tid = threadIdx.x;
    const int lane = tid & 63;
    const int w = tid >> 6;
    const int wm = w >> 1, wn = w & 1;
    const int m0 = blockIdx.x * 64;
    const int q = lane >> 4, q8 = q << 3, r15 = lane & 15;
    const int nb = wn * 96 + r15;

    #pragma unroll
    for (int it = 0; it < 6; ++it) {
        int c = it * 4 + w;
        int g = c / 6, sk = c - (c / 6) * 6;
        async_lds16(Ho + (size_t)(m0 + g * 16 + r15) * 192 + sk * 32 + q8, Lo + c * 1024);
    }
    __syncthreads();

    float4v acc[2][6];
    #pragma unroll
    for (int i = 0; i < 2; ++i)
        #pragma unroll
        for (int j = 0; j < 6; ++j)
            acc[i][j] = (float4v){0.f, 0.f, 0.f, 0.f};
    #pragma unroll
    for (int kk = 0; kk < 6; ++kk) {
        short8 af[2], wf[6];
        #pragma unroll
        for (int j = 0; j < 6; ++j)
            wf[j] = *(const short8*)(WOs + (((size_t)(wn * 6 + j) * 6 + kk) << 9) + lane * 8);
        #pragma unroll
        for (int i = 0; i < 2; ++i)
            af[i] = *(const short8*)(Lo + (((wm * 2 + i) * 6 + kk) << 10) + lane * 16);
        #pragma unroll
        for (int i = 0; i < 2; ++i)
            #pragma unroll
            for (int j = 0; j < 6; ++j)
                acc[i][j] = __builtin_amdgcn_mfma_f32_16x16x32_bf16(af[i], wf[j], acc[i][j], 0, 0, 0);
    }

    // residual, X write, LN stats
    #pragma unroll
    for (int j = 0; j < 6; ++j) {
        int n = nb + j * 16;
        float bv = BO[n];
        #pragma unroll
        for (int i = 0; i < 2; ++i) {
            int mrow = m0 + wm * 32 + i * 16 + q * 4;
            #pragma unroll
            for (int r = 0; r < 4; ++r) {
                acc[i][j][r] += bv + Xres[(size_t)(mrow + r) * 192 + n];
                Xres[(size_t)(mrow + r) * 192 + n] = acc[i][j][r];
            }
        }
    }
    #pragma unroll
    for (int i = 0; i < 2; ++i)
        #pragma unroll
        for (int r = 0; r < 4; ++r) {
            float s1 = 0.f, s2 = 0.f;
            #pragma unroll
            for (int j = 0; j < 6; ++j) { float v = acc[i][j][r]; s1 += v; s2 += v * v; }
            #pragma unroll
            for (int off = 1; off < 16; off <<= 1) {
                s1 += __shfl_xor(s1, off, 64);
                s2 += __shfl_xor(s2, off, 64);
            }
            if (r15 == 0) {
                int rl = wm * 32 + i * 16 + q * 4 + r;
                lsum[rl * 2 + wn] = s1;
                lsq[rl * 2 + wn] = s2;
            }
        }
    __syncthreads();
    #pragma unroll
    for (int i = 0; i < 2; ++i) {
        int g = wm * 2 + i;
        #pragma unroll
        for (int r = 0; r < 4; ++r) {
            int rl = g * 16 + q * 4 + r;
            float mean = (lsum[rl * 2] + lsum[rl * 2 + 1]) * (1.0f / 192.0f);
            float var = (lsq[rl * 2] + lsq[rl * 2 + 1]) * (1.0f / 192.0f) - mean * mean;
            float rstd = rsqrtf(var + 1e-5f);
            #pragma unroll
            for (int j = 0; j < 6; ++j) {
                int h = nb + j * 16;
                int base = (g * 6 + (h >> 5)) * 512 + ((h >> 3) & 3) * 128 + (h & 7);
                float v = (acc[i][j][r] - mean) * rstd * lng[h] + lnb[h];
                ((unsigned short*)Ap)[base + (q * 4 + r) * 8] = f2b(v);
            }
        }
    }
    __syncthreads();

    // QKV: 3 segments
    unsigned short* TB = (unsigned short*)Lo;
    for (int seg = 0; seg < 3; ++seg) {
        float4v a2[2][6];
        #pragma unroll
        for (int i = 0; i < 2; ++i)
            #pragma unroll
            for (int j = 0; j < 6; ++j)
                a2[i][j] = (float4v){0.f, 0.f, 0.f, 0.f};
        #pragma unroll
        for (int kk = 0; kk < 6; ++kk) {
            short8 af[2], wf[6];
            #pragma unroll
            for (int j = 0; j < 6; ++j)
                wf[j] = *(const short8*)(QKVs + (((size_t)(seg * 12 + wn * 6 + j) * 6 + kk) << 9) + lane * 8);
            #pragma unroll
            for (int i = 0; i < 2; ++i)
                af[i] = *(const short8*)(Ap + (((wm * 2 + i) * 6 + kk) << 10) + lane * 16);
            #pragma unroll
            for (int i = 0; i < 2; ++i)
                #pragma unroll
                for (int j = 0; j < 6; ++j)
                    a2[i][j] = __builtin_amdgcn_mfma_f32_16x16x32_bf16(af[i], wf[j], a2[i][j], 0, 0, 0);
        }
        __syncthreads();
        #pragma unroll
        for (int j = 0; j < 6; ++j) {
            float bv = bqkv[seg * 192 + nb + j * 16];
            #pragma unroll
            for (int i = 0; i < 2; ++i) {
                int row = wm * 32 + i * 16 + q * 4;
                #pragma unroll
                for (int r = 0; r < 4; ++r) {
                    float v = a2[i][j][r] + bv;
                    if (seg < 2) v = (v > 0.f) ? v + 1.f : expf(v);
                    if (seg == 0) v *= 0.14433756729740643f;
                    TB[(row + r) * 200 + nb + j * 16] = f2b(v);
                }
            }
        }
        __syncthreads();
        unsigned short* dst = (seg == 0) ? Qb : (seg == 1) ? Kb : Vb;
        #pragma unroll
        for (int it = 0; it < 6; ++it) {
            int idx = (it * 256 + tid) * 8;
            int row = idx / 192, col = idx - row * 192;
            *(short8*)(dst + (size_t)(m0 + row) * 192 + col) = *(const short8*)&TB[row * 200 + col];
        }
    }
}

// ---- WO + residual(reg) + LN + FFN + residual + LN + next-QKV ----
// launch_bounds (256,3): LDS 52224*3 = 153 KB fits 160 KB; VGPR 124 <= 170 -> 3 blocks/CU.
template<bool LASTB>
__global__ __launch_bounds__(256, 3)
void wo_ffn_qkv(const unsigned short* __restrict__ Ho,
                const unsigned short* __restrict__ WOs, const float* __restrict__ BO,
                float* __restrict__ Xres,
                const float* __restrict__ ln1g, const float* __restrict__ ln1b,
                const unsigned short* __restrict__ W1s, const float* __restrict__ B1,
                const unsigned short* __restrict__ W2s, const float* __restrict__ B2,
                const float* __restrict__ ln2g, const float* __restrict__ ln2b,
                const unsigned short* __restrict__ QKVs, const float* __restrict__ bqkv,
                unsigned short* __restrict__ Qb, unsigned short* __restrict__ Kb,
                unsigned short* __restrict__ Vb) {
    __shared__ __align__(16) unsigned char lds[52224];
    unsigned char* Lo = lds;
    float* lsum = (float*)(lds + 25600);
    float* lsq  = lsum + 128;
    unsigned char* Ap = lds + 27648;
    const int tid = threadIdx.x;
    const int lane = tid & 63;
    const int w = tid >> 6;
    const int wm = w >> 1, wn = w & 1;
    const int m0 = blockIdx.x * 64;
    const int q = lane >> 4, q8 = q << 3, r15 = lane & 15;
    const int nb = wn * 96 + r15;

    #pragma unroll
    for (int it = 0; it < 6; ++it) {
        int c = it * 4 + w;
        int g = c / 6, sk = c - (c / 6) * 6;
        async_lds16(Ho + (size_t)(m0 + g * 16 + r15) * 192 + sk * 32 + q8, Lo + c * 1024);
    }
    __syncthreads();

    float4v xres[2][6];
    #pragma unroll
    for (int i = 0; i < 2; ++i)
        #pragma unroll
        for (int j = 0; j < 6; ++j)
            xres[i][j] = (float4v){0.f, 0.f, 0.f, 0.f};
    #pragma unroll
    for (int kk = 0; kk < 6; ++kk) {
        short8 af[2], wf[6];
        #pragma unroll
        for (int j = 0; j < 6; ++j)
            wf[j] = *(const short8*)(WOs + (((size_t)(wn * 6 + j) * 6 + kk) << 9) + lane * 8);
        #pragma unroll
        for (int i = 0; i < 2; ++i)
            af[i] = *(const short8*)(Lo + (((wm * 2 + i) * 6 + kk) << 10) + lane * 16);
        #pragma unroll
        for (int i = 0; i < 2; ++i)
            #pragma unroll
            for (int j = 0; j < 6; ++j)
                xres[i][j] = __builtin_amdgcn_mfma_f32_16x16x32_bf16(af[i], wf[j], xres[i][j], 0, 0, 0);
    }
    // residual into registers (X read once; write deferred)
    #pragma unroll
    for (int j = 0; j < 6; ++j) {
        int n = nb + j * 16;
        float bv = BO[n];
        #pragma unroll
        for (int i = 0; i < 2; ++i) {
            int mrow = m0 + wm * 32 + i * 16 + q * 4;
            #pragma unroll
            for (int r = 0; r < 4; ++r)
                xres[i][j][r] += bv + Xres[(size_t)(mrow + r) * 192 + n];
        }
    }
    // LN1 stats + scatter A'
    #pragma unroll
    for (int i = 0; i < 2; ++i)
        #pragma unroll
        for (int r = 0; r < 4; ++r) {
            float s1 = 0.f, s2 = 0.f;
            #pragma unroll
            for (int j = 0; j < 6; ++j) { float v = xres[i][j][r]; s1 += v; s2 += v * v; }
            #pragma unroll
            for (int off = 1; off < 16; off <<= 1) {
                s1 += __shfl_xor(s1, off, 64);
                s2 += __shfl_xor(s2, off, 64);
            }
            if (r15 == 0) {
                int rl = wm * 32 + i * 16 + q * 4 + r;
                lsum[rl * 2 + wn] = s1;
                lsq[rl * 2 + wn] = s2;
            }
        }
    __syncthreads();
    #pragma unroll
    for (int i = 0; i < 2; ++i) {
        int g = wm * 2 + i;
        #pragma unroll
        for (int r = 0; r < 4; ++r) {
            int rl = g * 16 + q * 4 + r;
            float mean = (lsum[rl * 2] + lsum[rl * 2 + 1]) * (1.0f / 192.0f);
            float var = (lsq[rl * 2] + lsq[rl * 2 + 1]) * (1.0f / 192.0f) - mean * mean;
            float rstd = rsqrtf(var + 1e-5f);
            #pragma unroll
            for (int j = 0; j < 6; ++j) {
                int h = nb + j * 16;
                int base = (g * 6 + (h >> 5)) * 512 + ((h >> 3) & 3) * 128 + (h & 7);
                float v = (xres[i][j][r] - mean) * rstd * ln1g[h] + ln1b[h];
                ((unsigned short*)Ap)[base + (q * 4 + r) * 8] = f2b(v);
            }
        }
    }
    __syncthreads();

    // FFN: hidden chunks of 192, hidden lives only in LDS (Lo)
    float4v acc2[2][6];
    #pragma unroll
    for (int i = 0; i < 2; ++i)
        #pragma unroll
        for (int j = 0; j < 6; ++j)
            acc2[i][j] = (float4v){0.f, 0.f, 0.f, 0.f};
    for (int hc = 0; hc < 4; ++hc) {
        float4v acc1[2][6];
        #pragma unroll
        for (int i = 0; i < 2; ++i)
            #pragma unroll
            for (int j = 0; j < 6; ++j)
                acc1[i][j] = (float4v){0.f, 0.f, 0.f, 0.f};
        #pragma unroll
        for (int kk = 0; kk < 6; ++kk) {
            short8 af[2], wf[6];
            #pragma unroll
            for (int j = 0; j < 6; ++j)
                wf[j] = *(const short8*)(W1s + (((size_t)(hc * 12 + wn * 6 + j) * 6 + kk) << 9) + lane * 8);
            #pragma unroll
            for (int i = 0; i < 2; ++i)
                af[i] = *(const short8*)(Ap + (((wm * 2 + i) * 6 + kk) << 10) + lane * 16);
            #pragma unroll
            for (int i = 0; i < 2; ++i)
                #pragma unroll
                for (int j = 0; j < 6; ++j)
                    acc1[i][j] = __builtin_amdgcn_mfma_f32_16x16x32_bf16(af[i], wf[j], acc1[i][j], 0, 0, 0);
        }
        __syncthreads();
        #pragma unroll
        for (int i = 0; i < 2; ++i) {
            int g = wm * 2 + i;
            #pragma unroll
            for (int j = 0; j < 6; ++j) {
                int h = nb + j * 16;
                float bv = B1[hc * 192 + h];
                int base = (g * 6 + (h >> 5)) * 512 + ((h >> 3) & 3) * 128 + (h & 7);
                #pragma unroll
                for (int r = 0; r < 4; ++r) {
                    float v = acc1[i][j][r] + bv;
                    v = 0.5f * v * (1.0f + erff(v * 0.7071067811865475f));
                    ((unsigned short*)Lo)[base + (q * 4 + r) * 8] = f2b(v);
                }
            }
        }
        __syncthreads();
        #pragma unroll
        for (int kk = 0; kk < 6; ++kk) {
            short8 af[2], wf[6];
            #pragma unroll
            for (int j = 0; j < 6; ++j)
                wf[j] = *(const short8*)(W2s + (((size_t)(wn * 6 + j) * 24 + hc * 6 + kk) << 9) + lane * 8);
            #pragma unroll
            for (int i = 0; i < 2; ++i)
                af[i] = *(const short8*)(Lo + (((wm * 2 + i) * 6 + kk) << 10) + lane * 16);
            #pragma unroll
            for (int i = 0; i < 2; ++i)
                #pragma unroll
                for (int j = 0; j < 6; ++j)
                    acc2[i][j] = __builtin_amdgcn_mfma_f32_16x16x32_bf16(af[i], wf[j], acc2[i][j], 0, 0, 0);
        }
    }

    // FFN residual; single X write
    #pragma unroll
    for (int j = 0; j < 6; ++j) {
        int n = nb + j * 16;
        float bv = B2[n];
        #pragma unroll
        for (int i = 0; i < 2; ++i) {
            int mrow = m0 + wm * 32 + i * 16 + q * 4;
            #pragma unroll
            for (int r = 0; r < 4; ++r) {
                xres[i][j][r] += acc2[i][j][r] + bv;
                Xres[(size_t)(mrow + r) * 192 + n] = xres[i][j][r];
            }
        }
    }
    if (LASTB) return;

    // LN2 + next-block QKV
    #pragma unroll
    for (int i = 0; i < 2; ++i)
        #pragma unroll
        for (int r = 0; r < 4; ++r) {
            float s1 = 0.f, s2 = 0.f;
            #pragma unroll
            for (int j = 0; j < 6; ++j) { float v = xres[i][j][r]; s1 += v; s2 += v * v; }
            #pragma unroll
            for (int off = 1; off < 16; off <<= 1) {
                s1 += __shfl_xor(s1, off, 64);
                s2 += __shfl_xor(s2, off, 64);
            }
            if (r15 == 0) {
                int rl = wm * 32 + i * 16 + q * 4 + r;
                lsum[rl * 2 + wn] = s1;
                lsq[rl * 2 + wn] = s2;
            }
        }
    __syncthreads();
    #pragma unroll
    for (int i = 0; i < 2; ++i) {
        int g = wm * 2 + i;
        #pragma unroll
        for (int r = 0; r < 4; ++r) {
            int rl = g * 16 + q * 4 + r;
            float mean = (lsum[rl * 2] + lsum[rl * 2 + 1]) * (1.0f / 192.0f);
            float var = (lsq[rl * 2] + lsq[rl * 2 + 1]) * (1.0f / 192.0f) - mean * mean;
            float rstd = rsqrtf(var + 1e-5f);
            #pragma unroll
            for (int j = 0; j < 6; ++j) {
                int h = nb + j * 16;
                int base = (g * 6 + (h >> 5)) * 512 + ((h >> 3) & 3) * 128 + (h & 7);
                float v = (xres[i][j][r] - mean) * rstd * ln2g[h] + ln2b[h];
                ((unsigned short*)Ap)[base + (q * 4 + r) * 8] = f2b(v);
            }
        }
    }
    __syncthreads();

    unsigned short* TB = (unsigned short*)Lo;
    for (int seg = 0; seg < 3; ++seg) {
        float4v a2[2][6];
        #pragma unroll
        for (int i = 0; i < 2; ++i)
            #pragma unroll
            for (int j = 0; j < 6; ++j)
                a2[i][j] = (float4v){0.f, 0.f, 0.f, 0.f};
        #pragma unroll
        for (int kk = 0; kk < 6; ++kk) {
            short8 af[2], wf[6];
            #pragma unroll
            for (int j = 0; j < 6; ++j)
                wf[j] = *(const short8*)(QKVs + (((size_t)(seg * 12 + wn * 6 + j) * 6 + kk) << 9) + lane * 8);
            #pragma unroll
            for (int i = 0; i < 2; ++i)
                af[i] = *(const short8*)(Ap + (((wm * 2 + i) * 6 + kk) << 10) + lane * 16);
            #pragma unroll
            for (int i = 0; i < 2; ++i)
                #pragma unroll
                for (int j = 0; j < 6; ++j)
                    a2[i][j] = __builtin_amdgcn_mfma_f32_16x16x32_bf16(af[i], wf[j], a2[i][j], 0, 0, 0);
        }
        __syncthreads();
        #pragma unroll
        for (int j = 0; j < 6; ++j) {
            float bv = bqkv[seg * 192 + nb + j * 16];
            #pragma unroll
            for (int i = 0; i < 2; ++i) {
                int row = wm * 32 + i * 16 + q * 4;
                #pragma unroll
                for (int r = 0; r < 4; ++r) {
                    float v = a2[i][j][r] + bv;
                    if (seg < 2) v = (v > 0.f) ? v + 1.f : expf(v);
                    if (seg == 0) v *= 0.14433756729740643f;
                    TB[(row + r) * 200 + nb + j * 16] = f2b(v);
                }
            }
        }
        __syncthreads();
        unsigned short* dst = (seg == 0) ? Qb : (seg == 1) ? Kb : Vb;
        #pragma unroll
        for (int it = 0; it < 6; ++it) {
            int idx = (it * 256 + tid) * 8;
            int row = idx / 192, col = idx - row * 192;
            *(short8*)(dst + (size_t)(m0 + row) * 192 + col) = *(const short8*)&TB[row * 200 + col];
        }
    }
}

// ---------------- axial linear attention (separate Q/K/V [m][192] buffers) ----------------
template<int N, int MSTR>
__global__ __launch_bounds__(256) void attn_axial(const unsigned short* __restrict__ Qb,
                                                  const unsigned short* __restrict__ Kb,
                                                  const unsigned short* __restrict__ Vb,
                                                  unsigned short* __restrict__ O) {
    __shared__ unsigned short KV[32][400];
    __shared__ unsigned short kvs[4][64][72];
    const int tid = threadIdx.x;
    const int lane = tid & 63;
    const int w = tid >> 6;
    const int q = lane >> 4, r15 = lane & 15, q8 = q * 8;
    size_t base;
    if (MSTR == 1) base = (size_t)blockIdx.x * N;
    else           base = (size_t)(blockIdx.x >> 8) * 16384 + (blockIdx.x & 255);

    unsigned int* kz = (unsigned int*)&kvs[w][0][0];
    #pragma unroll
    for (int ii = 0; ii < 36; ++ii) kz[lane + ii * 64] = 0;

    short8 onesf;
    #pragma unroll
    for (int e = 0; e < 8; ++e) onesf[e] = (short)0x3F80;

    float4v kv[3][4];
    #pragma unroll
    for (int i = 0; i < 3; ++i)
        #pragma unroll
        for (int j = 0; j < 4; ++j)
            kv[i][j] = (float4v){0.f, 0.f, 0.f, 0.f};

    for (int ks = 0; ks < N; ks += 32) {
        #pragma unroll
        for (int it = 0; it < 6; ++it) {
            int cc = tid + it * 256;
            int row = cc / 48, c8 = cc - (cc / 48) * 48;
            size_t poff = (base + (size_t)(ks + row) * MSTR) * 192;
            const unsigned short* gp = (c8 < 24) ? (Kb + poff + c8 * 8) : (Vb + poff + (c8 - 24) * 8);
            *(short8*)&KV[row][c8 * 8] = *(const short8*)gp;
        }
        __syncthreads();
        short8 af[3], bf[3];
        #pragma unroll
        for (int t = 0; t < 3; ++t) {
            #pragma unroll
            for (int j = 0; j < 8; ++j) {
                af[t][j] = (short)KV[q8 + j][w * 48 + t * 16 + r15];
                bf[t][j] = (short)KV[q8 + j][192 + w * 48 + t * 16 + r15];
            }
        }
        #pragma unroll
        for (int i = 0; i < 3; ++i) {
            #pragma unroll
            for (int j = 0; j < 3; ++j)
                kv[i][j] = __builtin_amdgcn_mfma_f32_16x16x32_bf16(af[i], bf[j], kv[i][j], 0, 0, 0);
            kv[i][3] = __builtin_amdgcn_mfma_f32_16x16x32_bf16(af[i], onesf, kv[i][3], 0, 0, 0);
        }
        __syncthreads();
    }

    #pragma unroll
    for (int i = 0; i < 3; ++i) {
        #pragma unroll
        for (int j = 0; j < 3; ++j)
            #pragma unroll
            for (int r = 0; r < 4; ++r)
                kvs[w][j * 16 + r15][i * 16 + q * 4 + r] = f2b(kv[i][j][r]);
        if (r15 == 0)
            #pragma unroll
            for (int r = 0; r < 4; ++r)
                kvs[w][48][i * 16 + q * 4 + r] = f2b(kv[i][3][r]);
    }

    short8 bkv[2][4];
    #pragma unroll
    for (int kk = 0; kk < 2; ++kk)
        #pragma unroll
        for (int t = 0; t < 4; ++t)
            bkv[kk][t] = *(const short8*)&kvs[w][t * 16 + r15][kk * 32 + q8];

    for (int mt = 0; mt < N / 16; ++mt) {
        float4v o[4];
        #pragma unroll
        for (int t = 0; t < 4; ++t) o[t] = (float4v){0.f, 0.f, 0.f, 0.f};
        #pragma unroll
        for (int kk = 0; kk < 2; ++kk) {
            const unsigned short* qp = Qb + (base + (size_t)(mt * 16 + r15) * MSTR) * 192
                                       + w * 48 + kk * 32 + q8;
            short8 aq = *(const short8*)qp;
            #pragma unroll
            for (int t = 0; t < 4; ++t)
                o[t] = __builtin_amdgcn_mfma_f32_16x16x32_bf16(aq, bkv[kk][t], o[t], 0, 0, 0);
        }
        #pragma unroll
        for (int r = 0; r < 4; ++r) {
            float den = __shfl(o[3][r], q << 4);
            float z = 1.0f / (den + 1e-6f);
            int n = mt * 16 + q * 4 + r;
            unsigned short* op = O + (base + (size_t)n * MSTR) * 192 + w * 48;
            #pragma unroll
            for (int t = 0; t < 3; ++t)
                op[t * 16 + r15] = f2b(o[t][r] * z);
        }
    }
}

__global__ __launch_bounds__(256) void final_kernel(const float* __restrict__ X, const float* __restrict__ pw_w,
                                                    const float* __restrict__ pw_b, float* __restrict__ out) {
    int wave = threadIdx.x >> 6;
    int lane = threadIdx.x & 63;
    int p = blockIdx.x * 4 + wave;
    const float* xp = X + (size_t)p * CCH;
    float s = xp[lane] * pw_w[lane] + xp[lane + 64] * pw_w[lane + 64] + xp[lane + 128] * pw_w[lane + 128];
    #pragma unroll
    for (int off = 32; off; off >>= 1) s += __shfl_xor(s, off, 64);
    if (lane == 0) {
        float o = s + pw_b[0];
        float e = expf(o);
        out[p] = 1.0f - 1.0f / (2.0f + e);
    }
}

extern "C" void kernel_launch(void* const* d_in, const int* in_sizes, int n_in,
                              void* d_out, int out_size, void* d_ws, size_t ws_size,
                              hipStream_t stream) {
    const int*   tokens = (const int*)  d_in[0];
    const float* emb    = (const float*)d_in[1];
    const float* proj_w = (const float*)d_in[2];
    const float* proj_b = (const float*)d_in[3];
    const float* ln_g   = (const float*)d_in[4];
    const float* ln_b   = (const float*)d_in[5];
    const float* wq     = (const float*)d_in[6];
    const float* wk     = (const float*)d_in[7];
    const float* wv     = (const float*)d_in[8];
    const float* wo     = (const float*)d_in[9];
    const float* bq     = (const float*)d_in[10];
    const float* bk     = (const float*)d_in[11];
    const float* bv     = (const float*)d_in[12];
    const float* bo     = (const float*)d_in[13];
    const float* ffn_w1 = (const float*)d_in[14];
    const float* ffn_b1 = (const float*)d_in[15];
    const float* ffn_w2 = (const float*)d_in[16];
    const float* ffn_b2 = (const float*)d_in[17];
    const float* pw_w   = (const float*)d_in[18];
    const float* pw_b   = (const float*)d_in[19];

    float* X             = (float*)d_ws;
    unsigned short* Ho   = (unsigned short*)(X + BUF);
    unsigned short* Qb   = Ho + BUF;
    unsigned short* Kb   = Qb + BUF;
    unsigned short* Vb   = Kb + BUF;
    unsigned short* Eg   = Vb + BUF;                     // NP*64
    unsigned short* wqkvb = Eg + (size_t)NP * 64;
    const int QKVSZ = NBLK * 2 * 576 * CCH;
    const int WSZ   = NBLK * 2 * CCH * CCH;
    const int FSZ   = NBLK * 768 * CCH;
    unsigned short* wob = wqkvb + QKVSZ;
    unsigned short* w1b = wob + WSZ;
    unsigned short* w2b = w1b + FSZ;
    unsigned short* pjb = w2b + FSZ;                     // 12288
    float* bqkvb = (float*)(pjb + 12288 + 32);
    float* Xt = (float*)Qb;                              // proj tmp (aliases Qb/Kb, free pre-loop)

    wqkv_swz<<<QKVSZ / 256, 256, 0, stream>>>(wq, wk, wv, wqkvb);
    bqkv_concat<<<27, 256, 0, stream>>>(bq, bk, bv, bqkvb);
    swz_conv<192, 192><<<(WSZ + 255) / 256, 256, 0, stream>>>(wo, wob, NBLK * 2);
    swz_conv<768, 192><<<(FSZ + 255) / 256, 256, 0, stream>>>(ffn_w1, w1b, NBLK);
    swz_conv<192, 768><<<(FSZ + 255) / 256, 256, 0, stream>>>(ffn_w2, w2b, NBLK);
    swz_conv<192, 64><<<48, 256, 0, stream>>>(proj_w, pjb, 1);

    gather_kernel<<<NP * 64 / 256, 256, 0, stream>>>(tokens, emb, Eg);
    mm192<64, 1><<<dim3(1, NP / 64), 256, 0, stream>>>(Eg, pjb, proj_b,
                                                       nullptr, nullptr, nullptr, Xt, NP, CCH, 64);
    rotary_ln_kernel<<<NP / 4, 256, 0, stream>>>(Xt, X, Ho, ln_g, ln_b);
    mm192<128, 0><<<dim3(3, NP / 128), 256, 0, stream>>>(Ho, wqkvb, bqkvb,
                                                         Qb, Kb, Vb, nullptr, NP, 576, CCH);

    for (int i = 0; i < NBLK; ++i) {
        size_t wi0 = (size_t)(i * 2), wi1 = wi0 + 1;
        attn_axial<LL, 1><<<BB * SS, 256, 0, stream>>>(Qb, Kb, Vb, Ho);
        wo_qkv<<<NP / 64, 256, 0, stream>>>(Ho, wob + wi0 * CCH * CCH, bo + wi0 * CCH, X,
                                            ln_g + (size_t)(i * 3 + 1) * CCH, ln_b + (size_t)(i * 3 + 1) * CCH,
                                            wqkvb + wi1 * 576 * CCH, bqkvb + wi1 * 576, Qb, Kb, Vb);
        attn_axial<SS, LL><<<BB * LL, 256, 0, stream>>>(Qb, Kb, Vb, Ho);
        if (i < NBLK - 1) {
            size_t wn0 = (size_t)((i + 1) * 2);
            wo_ffn_qkv<false><<<NP / 64, 256, 0, stream>>>(
                Ho, wob + wi1 * CCH * CCH, bo + wi1 * CCH, X,
                ln_g + (size_t)(i * 3 + 2) * CCH, ln_b + (size_t)(i * 3 + 2) * CCH,
                w1b + (size_t)i * 768 * CCH, ffn_b1 + (size_t)i * 768,
                w2b + (size_t)i * CCH * 768, ffn_b2 + (size_t)i * CCH,
                ln_g + (size_t)((i + 1) * 3) * CCH, ln_b + (size_t)((i + 1) * 3) * CCH,
                wqkvb + wn0 * 576 * CCH, bqkvb + wn0 * 576, Qb, Kb, Vb);
        } else {
            wo_ffn_qkv<true><<<NP / 64, 256, 0, stream>>>(
                Ho, wob + wi1 * CCH * CCH, bo + wi1 * CCH, X,
                ln_g + (size_t)(i * 3 + 2) * CCH, ln_b + (size_t)(i * 3 + 2) * CCH,
                w1b + (size_t)i * 768 * CCH, ffn_b1 + (size_t)i * 768,
                w2b + (size_t)i * CCH * 768, ffn_b2 + (size_t)i * CCH,
                nullptr, nullptr, nullptr, nullptr, nullptr, nullptr, nullptr);
        }
    }
    final_kernel<<<NP / 4, 256, 0, stream>>>(X, pw_w, pw_b, (float*)d_out);
}

// Round 15
// 1053.676 us; speedup vs baseline: 1.1754x; 1.1754x over previous
//
#include <hip/hip_runtime.h>
#include <hip/hip_bf16.h>
#include <math.h>

#define NBLK 6
#define NH 4
#define CCH 192
#define BB 2
#define SS 64
#define LL 256
#define DH 48
#define NP (BB*SS*LL)            // 32768 pixels
#define BUF ((size_t)NP*CCH)

typedef __attribute__((ext_vector_type(8))) short short8;
typedef __attribute__((ext_vector_type(4))) float float4v;

__device__ __forceinline__ unsigned short f2b(float f) {
    union { float f; unsigned int u; } v; v.f = f;
    unsigned int r = v.u + 0x7FFF + ((v.u >> 16) & 1);
    return (unsigned short)(r >> 16);
}
__device__ __forceinline__ float b2f(unsigned short u) {
    union { unsigned int u; float f; } v; v.u = ((unsigned int)u) << 16;
    return v.f;
}
__device__ __forceinline__ void async_lds16(const void* g, void* l) {
    __builtin_amdgcn_global_load_lds(
        (const __attribute__((address_space(1))) unsigned int*)g,
        (__attribute__((address_space(3))) unsigned int*)l, 16, 0, 0);
}

// ---------- weight prep: fragment-major swizzle ----------
template<int N, int K>
__global__ void swz_conv(const float* __restrict__ src, unsigned short* __restrict__ dst, int layers) {
    int s = blockIdx.x * 256 + threadIdx.x;
    if (s >= layers * N * K) return;
    int li = s / (N * K);
    int t = s - li * (N * K);
    constexpr int KC = K / 32;
    int chunk = t >> 9, c = t & 511;
    int g = chunk / KC, sk = chunk - g * KC;
    int lane = c >> 3, ko = c & 7;
    int n = g * 16 + (lane & 15), k = sk * 32 + (lane >> 4) * 8 + ko;
    dst[s] = f2b(src[(size_t)li * N * K + (size_t)n * K + k]);
}
__global__ void wqkv_swz(const float* __restrict__ wq, const float* __restrict__ wk,
                         const float* __restrict__ wv, unsigned short* __restrict__ d) {
    int s = blockIdx.x * 256 + threadIdx.x;          // 12*576*192
    int wi = s / (576 * 192);
    int t = s - wi * 576 * 192;
    int chunk = t >> 9, c = t & 511;
    int g = chunk / 6, sk = chunk - g * 6;
    int lane = c >> 3, ko = c & 7;
    int n = g * 16 + (lane & 15), k = sk * 32 + (lane >> 4) * 8 + ko;
    int sg = n / 192, row = n - sg * 192;
    const float* src = (sg == 0) ? wq : (sg == 1) ? wk : wv;
    d[s] = f2b(src[(size_t)wi * 192 * 192 + (size_t)row * 192 + k]);
}
__global__ void bqkv_concat(const float* __restrict__ bq, const float* __restrict__ bk,
                            const float* __restrict__ bv, float* __restrict__ d) {
    int idx = blockIdx.x * 256 + threadIdx.x;        // 12*576
    if (idx >= NBLK * 2 * 576) return;
    int wi = idx / 576, n = idx - (idx / 576) * 576;
    int sg = n / 192, row = n - sg * 192;
    const float* src = (sg == 0) ? bq : (sg == 1) ? bk : bv;
    d[idx] = src[wi * CCH + row];
}

__global__ void gather_kernel(const int* __restrict__ tokens, const float* __restrict__ emb,
                              unsigned short* __restrict__ Eg) {
    int idx = blockIdx.x * 256 + threadIdx.x;   // NP*64
    int p = idx >> 6, c = idx & 63;
    Eg[idx] = f2b(emb[tokens[p] * 64 + c]);
}

// rotary + first LayerNorm fused; X stored bf16 (residual storage only — math fp32)
__global__ __launch_bounds__(256) void rotary_ln_kernel(const float* __restrict__ Xt,
                                                        unsigned short* __restrict__ X,
                                                        unsigned short* __restrict__ Hn,
                                                        const float* __restrict__ g, const float* __restrict__ b) {
    int wave = threadIdx.x >> 6;
    int lane = threadIdx.x & 63;
    int p = blockIdx.x * 4 + wave;
    int l = p & (LL - 1);
    const float* xp = Xt + (size_t)p * CCH;
    float v[3];
    #pragma unroll
    for (int i = 0; i < 3; ++i) {
        int c = lane + i * 64;
        int j = c % 96;
        float inv = expf((float)(2 * j) * (-9.210340371976184f / 192.0f));
        float ang = (float)l * inv;
        float part = (c < 96) ? -xp[c + 96] : xp[c - 96];
        v[i] = xp[c] * cosf(ang) + part * sinf(ang);
    }
    float s = v[0] + v[1] + v[2];
    float qq = v[0] * v[0] + v[1] * v[1] + v[2] * v[2];
    #pragma unroll
    for (int off = 32; off; off >>= 1) {
        s += __shfl_xor(s, off, 64);
        qq += __shfl_xor(qq, off, 64);
    }
    float mean = s * (1.0f / 192.0f);
    float var = qq * (1.0f / 192.0f) - mean * mean;
    float r = rsqrtf(var + 1e-5f);
    unsigned short* op = X + (size_t)p * CCH;
    unsigned short* hp = Hn + (size_t)p * CCH;
    #pragma unroll
    for (int i = 0; i < 3; ++i) {
        int c = lane + i * 64;
        op[c] = f2b(v[i]);
        hp[c] = f2b((v[i] - mean) * r * g[c] + b[c]);
    }
}

// ---------------- bf16 MFMA GEMM (pre-loop only: proj, block-0 QKV) ----------------
template<int MT, int EPI>
__global__ __launch_bounds__(256, (MT == 128) ? 3 : 4)
void mm192(const unsigned short* __restrict__ A, const unsigned short* __restrict__ Wsw,
           const float* __restrict__ bias,
           unsigned short* __restrict__ O0, unsigned short* __restrict__ O1,
           unsigned short* __restrict__ O2,
           float* __restrict__ Of,
           int M, int N, int K) {
    constexpr int NI = MT / 32;
    __shared__ __align__(16) unsigned char lds[(MT == 128) ? 51200 : 28672];
    const int tid = threadIdx.x;
    const int lane = tid & 63;
    const int w = tid >> 6;
    const int wm = w >> 1, wn = w & 1;
    const int m0 = blockIdx.y * MT;
    const int g0 = blockIdx.x * 12;
    const int q = lane >> 4;
    const int q8 = q << 3;
    const int r15 = lane & 15;
    const int KC = K >> 5;

    for (int c = w; c < (MT / 16) * KC; c += 4) {
        int g = c / KC, sk = c - g * KC;
        async_lds16(A + (size_t)(m0 + g * 16 + r15) * K + sk * 32 + q8, lds + c * 1024);
    }

    float4v acc[NI][6];
    #pragma unroll
    for (int i = 0; i < NI; ++i)
        #pragma unroll
        for (int j = 0; j < 6; ++j)
            acc[i][j] = (float4v){0.f, 0.f, 0.f, 0.f};

    __syncthreads();

    for (int sk = 0; sk < KC; ++sk) {
        short8 af[NI], wf[6];
        #pragma unroll
        for (int j = 0; j < 6; ++j)
            wf[j] = *(const short8*)(Wsw + (((size_t)(g0 + wn * 6 + j) * KC + sk) << 9) + lane * 8);
        #pragma unroll
        for (int i = 0; i < NI; ++i)
            af[i] = *(const short8*)(lds + (((wm * NI + i) * KC + sk) << 10) + lane * 16);
        #pragma unroll
        for (int i = 0; i < NI; ++i)
            #pragma unroll
            for (int j = 0; j < 6; ++j)
                acc[i][j] = __builtin_amdgcn_mfma_f32_16x16x32_bf16(af[i], wf[j], acc[i][j], 0, 0, 0);
    }

    const int nb = blockIdx.x * 192 + wn * 96 + r15;
    const int mb = m0 + wm * (MT / 2) + q * 4;

    if (EPI == 0) {
        unsigned short* TB = (unsigned short*)lds;
        const int bx = blockIdx.x;
        __syncthreads();
        #pragma unroll
        for (int j = 0; j < 6; ++j) {
            float bv = bias[nb + j * 16];
            #pragma unroll
            for (int i = 0; i < NI; ++i) {
                int row = wm * (MT / 2) + i * 16 + q * 4;
                #pragma unroll
                for (int r = 0; r < 4; ++r) {
                    float v = acc[i][j][r] + bv;
                    if (bx < 2) v = (v > 0.f) ? v + 1.f : expf(v);
                    if (bx == 0) v *= 0.14433756729740643f;
                    TB[(row + r) * 200 + wn * 96 + j * 16 + r15] = f2b(v);
                }
            }
        }
        __syncthreads();
        unsigned short* dst = (bx == 0) ? O0 : (bx == 1) ? O1 : O2;
        #pragma unroll
        for (int it = 0; it < (MT * 192) / 2048; ++it) {
            int idx = (it * 256 + tid) * 8;
            int row = idx / 192, col = idx - row * 192;
            *(short8*)(dst + (size_t)(m0 + row) * 192 + col) = *(const short8*)&TB[row * 200 + col];
        }
    } else {
        #pragma unroll
        for (int j = 0; j < 6; ++j) {
            int n = nb + j * 16;
            float bv = bias[n];
            #pragma unroll
            for (int i = 0; i < NI; ++i) {
                int mrow = mb + i * 16;
                #pragma unroll
                for (int r = 0; r < 4; ++r)
                    Of[(size_t)(mrow + r) * N + n] = acc[i][j][r] + bv;
            }
        }
    }
}

// ================= fused per-pixel GEMM chains (64 rows/block, grid = NP/64) =================
// LDS (52224 B): Lo [0,25600) staging/Hreg/TB | stats [25600,26624) | Ap [27648,52224)
// X residual stream stored bf16; all accumulation fp32.

// ---- WO + residual + LN + QKV ----
__global__ __launch_bounds__(256, 3)
void wo_qkv(const unsigned short* __restrict__ Ho,
            const unsigned short* __restrict__ WOs, const float* __restrict__ BO,
            unsigned short* __restrict__ Xres,
            const float* __restrict__ lng, const float* __restrict__ lnb,
            const unsigned short* __restrict__ QKVs, const float* __restrict__ bqkv,
            unsigned short* __restrict__ Qb, unsigned short* __restrict__ Kb,
            unsigned short* __restrict__ Vb) {
    __shared__ __align__(16) unsigned char lds[52224];
    unsigned char* Lo = lds;
    float* lsum = (float*)(lds + 25600);
    float* lsq  = lsum + 128;
    unsigned char* Ap = lds + 27648;
    const int tid = threadIdx.x;
    const int lane = tid & 63;
    const int w = tid >> 6;
    const int wm = w >> 1, wn = w & 1;
    const int m0 = blockIdx.x * 64;
    const int q = lane >> 4, q8 = q << 3, r15 = lane & 15;
    const int nb = wn * 96 + r15;

    #pragma unroll
    for (int it = 0; it < 6; ++it) {
        int c = it * 4 + w;
        int g = c / 6, sk = c - (c / 6) * 6;
        async_lds16(Ho + (size_t)(m0 + g * 16 + r15) * 192 + sk * 32 + q8, Lo + c * 1024);
    }
    __syncthreads();

    float4v acc[2][6];
    #pragma unroll
    for (int i = 0; i < 2; ++i)
        #pragma unroll
        for (int j = 0; j < 6; ++j)
            acc[i][j] = (float4v){0.f, 0.f, 0.f, 0.f};
    #pragma unroll
    for (int kk = 0; kk < 6; ++kk) {
        short8 af[2], wf[6];
        #pragma unroll
        for (int j = 0; j < 6; ++j)
            wf[j] = *(const short8*)(WOs + (((size_t)(wn * 6 + j) * 6 + kk) << 9) + lane * 8);
        #pragma unroll
        for (int i = 0; i < 2; ++i)
            af[i] = *(const short8*)(Lo + (((wm * 2 + i) * 6 + kk) << 10) + lane * 16);
        #pragma unroll
        for (int i = 0; i < 2; ++i)
            #pragma unroll
            for (int j = 0; j < 6; ++j)
                acc[i][j] = __builtin_amdgcn_mfma_f32_16x16x32_bf16(af[i], wf[j], acc[i][j], 0, 0, 0);
    }

    // residual, X write (bf16), LN stats
    #pragma unroll
    for (int j = 0; j < 6; ++j) {
        int n = nb + j * 16;
        float bv = BO[n];
        #pragma unroll
        for (int i = 0; i < 2; ++i) {
            int mrow = m0 + wm * 32 + i * 16 + q * 4;
            #pragma unroll
            for (int r = 0; r < 4; ++r) {
                acc[i][j][r] += bv + b2f(Xres[(size_t)(mrow + r) * 192 + n]);
                Xres[(size_t)(mrow + r) * 192 + n] = f2b(acc[i][j][r]);
            }
        }
    }
    #pragma unroll
    for (int i = 0; i < 2; ++i)
        #pragma unroll
        for (int r = 0; r < 4; ++r) {
            float s1 = 0.f, s2 = 0.f;
            #pragma unroll
            for (int j = 0; j < 6; ++j) { float v = acc[i][j][r]; s1 += v; s2 += v * v; }
            #pragma unroll
            for (int off = 1; off < 16; off <<= 1) {
                s1 += __shfl_xor(s1, off, 64);
                s2 += __shfl_xor(s2, off, 64);
            }
            if (r15 == 0) {
                int rl = wm * 32 + i * 16 + q * 4 + r;
                lsum[rl * 2 + wn] = s1;
                lsq[rl * 2 + wn] = s2;
            }
        }
    __syncthreads();
    #pragma unroll
    for (int i = 0; i < 2; ++i) {
        int g = wm * 2 + i;
        #pragma unroll
        for (int r = 0; r < 4; ++r) {
            int rl = g * 16 + q * 4 + r;
            float mean = (lsum[rl * 2] + lsum[rl * 2 + 1]) * (1.0f / 192.0f);
            float var = (lsq[rl * 2] + lsq[rl * 2 + 1]) * (1.0f / 192.0f) - mean * mean;
            float rstd = rsqrtf(var + 1e-5f);
            #pragma unroll
            for (int j = 0; j < 6; ++j) {
                int h = nb + j * 16;
                int base = (g * 6 + (h >> 5)) * 512 + ((h >> 3) & 3) * 128 + (h & 7);
                float v = (acc[i][j][r] - mean) * rstd * lng[h] + lnb[h];
                ((unsigned short*)Ap)[base + (q * 4 + r) * 8] = f2b(v);
            }
        }
    }
    __syncthreads();

    // QKV: 3 segments
    unsigned short* TB = (unsigned short*)Lo;
    for (int seg = 0; seg < 3; ++seg) {
        float4v a2[2][6];
        #pragma unroll
        for (int i = 0; i < 2; ++i)
            #pragma unroll
            for (int j = 0; j < 6; ++j)
                a2[i][j] = (float4v){0.f, 0.f, 0.f, 0.f};
        #pragma unroll
        for (int kk = 0; kk < 6; ++kk) {
            short8 af[2], wf[6];
            #pragma unroll
            for (int j = 0; j < 6; ++j)
                wf[j] = *(const short8*)(QKVs + (((size_t)(seg * 12 + wn * 6 + j) * 6 + kk) << 9) + lane * 8);
            #pragma unroll
            for (int i = 0; i < 2; ++i)
                af[i] = *(const short8*)(Ap + (((wm * 2 + i) * 6 + kk) << 10) + lane * 16);
            #pragma unroll
            for (int i = 0; i < 2; ++i)
                #pragma unroll
                for (int j = 0; j < 6; ++j)
                    a2[i][j] = __builtin_amdgcn_mfma_f32_16x16x32_bf16(af[i], wf[j], a2[i][j], 0, 0, 0);
        }
        __syncthreads();
        #pragma unroll
        for (int j = 0; j < 6; ++j) {
            float bv = bqkv[seg * 192 + nb + j * 16];
            #pragma unroll
            for (int i = 0; i < 2; ++i) {
                int row = wm * 32 + i * 16 + q * 4;
                #pragma unroll
                for (int r = 0; r < 4; ++r) {
                    float v = a2[i][j][r] + bv;
                    if (seg < 2) v = (v > 0.f) ? v + 1.f : expf(v);
                    if (seg == 0) v *= 0.14433756729740643f;
                    TB[(row + r) * 200 + nb + j * 16] = f2b(v);
                }
            }
        }
        __syncthreads();
        unsigned short* dst = (seg == 0) ? Qb : (seg == 1) ? Kb : Vb;
        #pragma unroll
        for (int it = 0; it < 6; ++it) {
            int idx = (it * 256 + tid) * 8;
            int row = idx / 192, col = idx - row * 192;
            *(short8*)(dst + (size_t)(m0 + row) * 192 + col) = *(const short8*)&TB[row * 200 + col];
        }
    }
}

// ---- WO + residual(reg) + LN + FFN + residual + LN + next-QKV ----
// (256,2): needs ~124 VGPR for the three fp32 accumulator sets — forcing 3 spills (R14).
template<bool LASTB>
__global__ __launch_bounds__(256, 2)
void wo_ffn_qkv(const unsigned short* __restrict__ Ho,
                const unsigned short* __restrict__ WOs, const float* __restrict__ BO,
                unsigned short* __restrict__ Xres,
                const float* __restrict__ ln1g, const float* __restrict__ ln1b,
                const unsigned short* __restrict__ W1s, const float* __restrict__ B1,
                const unsigned short* __restrict__ W2s, const float* __restrict__ B2,
                const float* __restrict__ ln2g, const float* __restrict__ ln2b,
                const unsigned short* __restrict__ QKVs, const float* __restrict__ bqkv,
                unsigned short* __restrict__ Qb, unsigned short* __restrict__ Kb,
                unsigned short* __restrict__ Vb) {
    __shared__ __align__(16) unsigned char lds[52224];
    unsigned char* Lo = lds;
    float* lsum = (float*)(lds + 25600);
    float* lsq  = lsum + 128;
    unsigned char* Ap = lds + 27648;
    const int tid = threadIdx.x;
    const int lane = tid & 63;
    const int w = tid >> 6;
    const int wm = w >> 1, wn = w & 1;
    const int m0 = blockIdx.x * 64;
    const int q = lane >> 4, q8 = q << 3, r15 = lane & 15;
    const int nb = wn * 96 + r15;

    #pragma unroll
    for (int it = 0; it < 6; ++it) {
        int c = it * 4 + w;
        int g = c / 6, sk = c - (c / 6) * 6;
        async_lds16(Ho + (size_t)(m0 + g * 16 + r15) * 192 + sk * 32 + q8, Lo + c * 1024);
    }
    __syncthreads();

    float4v xres[2][6];
    #pragma unroll
    for (int i = 0; i < 2; ++i)
        #pragma unroll
        for (int j = 0; j < 6; ++j)
            xres[i][j] = (float4v){0.f, 0.f, 0.f, 0.f};
    #pragma unroll
    for (int kk = 0; kk < 6; ++kk) {
        short8 af[2], wf[6];
        #pragma unroll
        for (int j = 0; j < 6; ++j)
            wf[j] = *(const short8*)(WOs + (((size_t)(wn * 6 + j) * 6 + kk) << 9) + lane * 8);
        #pragma unroll
        for (int i = 0; i < 2; ++i)
            af[i] = *(const short8*)(Lo + (((wm * 2 + i) * 6 + kk) << 10) + lane * 16);
        #pragma unroll
        for (int i = 0; i < 2; ++i)
            #pragma unroll
            for (int j = 0; j < 6; ++j)
                xres[i][j] = __builtin_amdgcn_mfma_f32_16x16x32_bf16(af[i], wf[j], xres[i][j], 0, 0, 0);
    }
    // residual into registers (X read once; write deferred)
    #pragma unroll
    for (int j = 0; j < 6; ++j) {
        int n = nb + j * 16;
        float bv = BO[n];
        #pragma unroll
        for (int i = 0; i < 2; ++i) {
            int mrow = m0 + wm * 32 + i * 16 + q * 4;
            #pragma unroll
            for (int r = 0; r < 4; ++r)
                xres[i][j][r] += bv + b2f(Xres[(size_t)(mrow + r) * 192 + n]);
        }
    }
    // LN1 stats + scatter A'
    #pragma unroll
    for (int i = 0; i < 2; ++i)
        #pragma unroll
        for (int r = 0; r < 4; ++r) {
            float s1 = 0.f, s2 = 0.f;
            #pragma unroll
            for (int j = 0; j < 6; ++j) { float v = xres[i][j][r]; s1 += v; s2 += v * v; }
            #pragma unroll
            for (int off = 1; off < 16; off <<= 1) {
                s1 += __shfl_xor(s1, off, 64);
                s2 += __shfl_xor(s2, off, 64);
            }
            if (r15 == 0) {
                int rl = wm * 32 + i * 16 + q * 4 + r;
                lsum[rl * 2 + wn] = s1;
                lsq[rl * 2 + wn] = s2;
            }
        }
    __syncthreads();
    #pragma unroll
    for (int i = 0; i < 2; ++i) {
        int g = wm * 2 + i;
        #pragma unroll
        for (int r = 0; r < 4; ++r) {
            int rl = g * 16 + q * 4 + r;
            float mean = (lsum[rl * 2] + lsum[rl * 2 + 1]) * (1.0f / 192.0f);
            float var = (lsq[rl * 2] + lsq[rl * 2 + 1]) * (1.0f / 192.0f) - mean * mean;
            float rstd = rsqrtf(var + 1e-5f);
            #pragma unroll
            for (int j = 0; j < 6; ++j) {
                int h = nb + j * 16;
                int base = (g * 6 + (h >> 5)) * 512 + ((h >> 3) & 3) * 128 + (h & 7);
                float v = (xres[i][j][r] - mean) * rstd * ln1g[h] + ln1b[h];
                ((unsigned short*)Ap)[base + (q * 4 + r) * 8] = f2b(v);
            }
        }
    }
    __syncthreads();

    // FFN: hidden chunks of 192, hidden lives only in LDS (Lo)
    float4v acc2[2][6];
    #pragma unroll
    for (int i = 0; i < 2; ++i)
        #pragma unroll
        for (int j = 0; j < 6; ++j)
            acc2[i][j] = (float4v){0.f, 0.f, 0.f, 0.f};
    for (int hc = 0; hc < 4; ++hc) {
        float4v acc1[2][6];
        #pragma unroll
        for (int i = 0; i < 2; ++i)
            #pragma unroll
            for (int j = 0; j < 6; ++j)
                acc1[i][j] = (float4v){0.f, 0.f, 0.f, 0.f};
        #pragma unroll
        for (int kk = 0; kk < 6; ++kk) {
            short8 af[2], wf[6];
            #pragma unroll
            for (int j = 0; j < 6; ++j)
                wf[j] = *(const short8*)(W1s + (((size_t)(hc * 12 + wn * 6 + j) * 6 + kk) << 9) + lane * 8);
            #pragma unroll
            for (int i = 0; i < 2; ++i)
                af[i] = *(const short8*)(Ap + (((wm * 2 + i) * 6 + kk) << 10) + lane * 16);
            #pragma unroll
            for (int i = 0; i < 2; ++i)
                #pragma unroll
                for (int j = 0; j < 6; ++j)
                    acc1[i][j] = __builtin_amdgcn_mfma_f32_16x16x32_bf16(af[i], wf[j], acc1[i][j], 0, 0, 0);
        }
        __syncthreads();
        #pragma unroll
        for (int i = 0; i < 2; ++i) {
            int g = wm * 2 + i;
            #pragma unroll
            for (int j = 0; j < 6; ++j) {
                int h = nb + j * 16;
                float bv = B1[hc * 192 + h];
                int base = (g * 6 + (h >> 5)) * 512 + ((h >> 3) & 3) * 128 + (h & 7);
                #pragma unroll
                for (int r = 0; r < 4; ++r) {
                    float v = acc1[i][j][r] + bv;
                    v = 0.5f * v * (1.0f + erff(v * 0.7071067811865475f));
                    ((unsigned short*)Lo)[base + (q * 4 + r) * 8] = f2b(v);
                }
            }
        }
        __syncthreads();
        #pragma unroll
        for (int kk = 0; kk < 6; ++kk) {
            short8 af[2], wf[6];
            #pragma unroll
            for (int j = 0; j < 6; ++j)
                wf[j] = *(const short8*)(W2s + (((size_t)(wn * 6 + j) * 24 + hc * 6 + kk) << 9) + lane * 8);
            #pragma unroll
            for (int i = 0; i < 2; ++i)
                af[i] = *(const short8*)(Lo + (((wm * 2 + i) * 6 + kk) << 10) + lane * 16);
            #pragma unroll
            for (int i = 0; i < 2; ++i)
                #pragma unroll
                for (int j = 0; j < 6; ++j)
                    acc2[i][j] = __builtin_amdgcn_mfma_f32_16x16x32_bf16(af[i], wf[j], acc2[i][j], 0, 0, 0);
        }
    }

    // FFN residual; single X write (bf16)
    #pragma unroll
    for (int j = 0; j < 6; ++j) {
        int n = nb + j * 16;
        float bv = B2[n];
        #pragma unroll
        for (int i = 0; i < 2; ++i) {
            int mrow = m0 + wm * 32 + i * 16 + q * 4;
            #pragma unroll
            for (int r = 0; r < 4; ++r) {
                xres[i][j][r] += acc2[i][j][r] + bv;
                Xres[(size_t)(mrow + r) * 192 + n] = f2b(xres[i][j][r]);
            }
        }
    }
    if (LASTB) return;

    // LN2 + next-block QKV
    #pragma unroll
    for (int i = 0; i < 2; ++i)
        #pragma unroll
        for (int r = 0; r < 4; ++r) {
            float s1 = 0.f, s2 = 0.f;
            #pragma unroll
            for (int j = 0; j < 6; ++j) { float v = xres[i][j][r]; s1 += v; s2 += v * v; }
            #pragma unroll
            for (int off = 1; off < 16; off <<= 1) {
                s1 += __shfl_xor(s1, off, 64);
                s2 += __shfl_xor(s2, off, 64);
            }
            if (r15 == 0) {
                int rl = wm * 32 + i * 16 + q * 4 + r;
                lsum[rl * 2 + wn] = s1;
                lsq[rl * 2 + wn] = s2;
            }
        }
    __syncthreads();
    #pragma unroll
    for (int i = 0; i < 2; ++i) {
        int g = wm * 2 + i;
        #pragma unroll
        for (int r = 0; r < 4; ++r) {
            int rl = g * 16 + q * 4 + r;
            float mean = (lsum[rl * 2] + lsum[rl * 2 + 1]) * (1.0f / 192.0f);
            float var = (lsq[rl * 2] + lsq[rl * 2 + 1]) * (1.0f / 192.0f) - mean * mean;
            float rstd = rsqrtf(var + 1e-5f);
            #pragma unroll
            for (int j = 0; j < 6; ++j) {
                int h = nb + j * 16;
                int base = (g * 6 + (h >> 5)) * 512 + ((h >> 3) & 3) * 128 + (h & 7);
                float v = (xres[i][j][r] - mean) * rstd * ln2g[h] + ln2b[h];
                ((unsigned short*)Ap)[base + (q * 4 + r) * 8] = f2b(v);
            }
        }
    }
    __syncthreads();

    unsigned short* TB = (unsigned short*)Lo;
    for (int seg = 0; seg < 3; ++seg) {
        float4v a2[2][6];
        #pragma unroll
        for (int i = 0; i < 2; ++i)
            #pragma unroll
            for (int j = 0; j < 6; ++j)
                a2[i][j] = (float4v){0.f, 0.f, 0.f, 0.f};
        #pragma unroll
        for (int kk = 0; kk < 6; ++kk) {
            short8 af[2], wf[6];
            #pragma unroll
            for (int j = 0; j < 6; ++j)
                wf[j] = *(const short8*)(QKVs + (((size_t)(seg * 12 + wn * 6 + j) * 6 + kk) << 9) + lane * 8);
            #pragma unroll
            for (int i = 0; i < 2; ++i)
                af[i] = *(const short8*)(Ap + (((wm * 2 + i) * 6 + kk) << 10) + lane * 16);
            #pragma unroll
            for (int i = 0; i < 2; ++i)
                #pragma unroll
                for (int j = 0; j < 6; ++j)
                    a2[i][j] = __builtin_amdgcn_mfma_f32_16x16x32_bf16(af[i], wf[j], a2[i][j], 0, 0, 0);
        }
        __syncthreads();
        #pragma unroll
        for (int j = 0; j < 6; ++j) {
            float bv = bqkv[seg * 192 + nb + j * 16];
            #pragma unroll
            for (int i = 0; i < 2; ++i) {
                int row = wm * 32 + i * 16 + q * 4;
                #pragma unroll
                for (int r = 0; r < 4; ++r) {
                    float v = a2[i][j][r] + bv;
                    if (seg < 2) v = (v > 0.f) ? v + 1.f : expf(v);
                    if (seg == 0) v *= 0.14433756729740643f;
                    TB[(row + r) * 200 + nb + j * 16] = f2b(v);
                }
            }
        }
        __syncthreads();
        unsigned short* dst = (seg == 0) ? Qb : (seg == 1) ? Kb : Vb;
        #pragma unroll
        for (int it = 0; it < 6; ++it) {
            int idx = (it * 256 + tid) * 8;
            int row = idx / 192, col = idx - row * 192;
            *(short8*)(dst + (size_t)(m0 + row) * 192 + col) = *(const short8*)&TB[row * 200 + col];
        }
    }
}

// ---------------- axial linear attention (separate Q/K/V [m][192] buffers) ----------------
template<int N, int MSTR>
__global__ __launch_bounds__(256) void attn_axial(const unsigned short* __restrict__ Qb,
                                                  const unsigned short* __restrict__ Kb,
                                                  const unsigned short* __restrict__ Vb,
                                                  unsigned short* __restrict__ O) {
    __shared__ unsigned short KV[32][400];
    __shared__ unsigned short kvs[4][64][72];
    const int tid = threadIdx.x;
    const int lane = tid & 63;
    const int w = tid >> 6;
    const int q = lane >> 4, r15 = lane & 15, q8 = q * 8;
    size_t base;
    if (MSTR == 1) base = (size_t)blockIdx.x * N;
    else           base = (size_t)(blockIdx.x >> 8) * 16384 + (blockIdx.x & 255);

    unsigned int* kz = (unsigned int*)&kvs[w][0][0];
    #pragma unroll
    for (int ii = 0; ii < 36; ++ii) kz[lane + ii * 64] = 0;

    short8 onesf;
    #pragma unroll
    for (int e = 0; e < 8; ++e) onesf[e] = (short)0x3F80;

    float4v kv[3][4];
    #pragma unroll
    for (int i = 0; i < 3; ++i)
        #pragma unroll
        for (int j = 0; j < 4; ++j)
            kv[i][j] = (float4v){0.f, 0.f, 0.f, 0.f};

    for (int ks = 0; ks < N; ks += 32) {
        #pragma unroll
        for (int it = 0; it < 6; ++it) {
            int cc = tid + it * 256;
            int row = cc / 48, c8 = cc - (cc / 48) * 48;
            size_t poff = (base + (size_t)(ks + row) * MSTR) * 192;
            const unsigned short* gp = (c8 < 24) ? (Kb + poff + c8 * 8) : (Vb + poff + (c8 - 24) * 8);
            *(short8*)&KV[row][c8 * 8] = *(const short8*)gp;
        }
        __syncthreads();
        short8 af[3], bf[3];
        #pragma unroll
        for (int t = 0; t < 3; ++t) {
            #pragma unroll
            for (int j = 0; j < 8; ++j) {
                af[t][j] = (short)KV[q8 + j][w * 48 + t * 16 + r15];
                bf[t][j] = (short)KV[q8 + j][192 + w * 48 + t * 16 + r15];
            }
        }
        #pragma unroll
        for (int i = 0; i < 3; ++i) {
            #pragma unroll
            for (int j = 0; j < 3; ++j)
                kv[i][j] = __builtin_amdgcn_mfma_f32_16x16x32_bf16(af[i], bf[j], kv[i][j], 0, 0, 0);
            kv[i][3] = __builtin_amdgcn_mfma_f32_16x16x32_bf16(af[i], onesf, kv[i][3], 0, 0, 0);
        }
        __syncthreads();
    }

    #pragma unroll
    for (int i = 0; i < 3; ++i) {
        #pragma unroll
        for (int j = 0; j < 3; ++j)
            #pragma unroll
            for (int r = 0; r < 4; ++r)
                kvs[w][j * 16 + r15][i * 16 + q * 4 + r] = f2b(kv[i][j][r]);
        if (r15 == 0)
            #pragma unroll
            for (int r = 0; r < 4; ++r)
                kvs[w][48][i * 16 + q * 4 + r] = f2b(kv[i][3][r]);
    }

    short8 bkv[2][4];
    #pragma unroll
    for (int kk = 0; kk < 2; ++kk)
        #pragma unroll
        for (int t = 0; t < 4; ++t)
            bkv[kk][t] = *(const short8*)&kvs[w][t * 16 + r15][kk * 32 + q8];

    for (int mt = 0; mt < N / 16; ++mt) {
        float4v o[4];
        #pragma unroll
        for (int t = 0; t < 4; ++t) o[t] = (float4v){0.f, 0.f, 0.f, 0.f};
        #pragma unroll
        for (int kk = 0; kk < 2; ++kk) {
            const unsigned short* qp = Qb + (base + (size_t)(mt * 16 + r15) * MSTR) * 192
                                       + w * 48 + kk * 32 + q8;
            short8 aq = *(const short8*)qp;
            #pragma unroll
            for (int t = 0; t < 4; ++t)
                o[t] = __builtin_amdgcn_mfma_f32_16x16x32_bf16(aq, bkv[kk][t], o[t], 0, 0, 0);
        }
        #pragma unroll
        for (int r = 0; r < 4; ++r) {
            float den = __shfl(o[3][r], q << 4);
            float z = 1.0f / (den + 1e-6f);
            int n = mt * 16 + q * 4 + r;
            unsigned short* op = O + (base + (size_t)n * MSTR) * 192 + w * 48;
            #pragma unroll
            for (int t = 0; t < 3; ++t)
                op[t * 16 + r15] = f2b(o[t][r] * z);
        }
    }
}

__global__ __launch_bounds__(256) void final_kernel(const unsigned short* __restrict__ X,
                                                    const float* __restrict__ pw_w,
                                                    const float* __restrict__ pw_b, float* __restrict__ out) {
    int wave = threadIdx.x >> 6;
    int lane = threadIdx.x & 63;
    int p = blockIdx.x * 4 + wave;
    const unsigned short* xp = X + (size_t)p * CCH;
    float s = b2f(xp[lane]) * pw_w[lane] + b2f(xp[lane + 64]) * pw_w[lane + 64]
            + b2f(xp[lane + 128]) * pw_w[lane + 128];
    #pragma unroll
    for (int off = 32; off; off >>= 1) s += __shfl_xor(s, off, 64);
    if (lane == 0) {
        float o = s + pw_b[0];
        float e = expf(o);
        out[p] = 1.0f - 1.0f / (2.0f + e);
    }
}

extern "C" void kernel_launch(void* const* d_in, const int* in_sizes, int n_in,
                              void* d_out, int out_size, void* d_ws, size_t ws_size,
                              hipStream_t stream) {
    const int*   tokens = (const int*)  d_in[0];
    const float* emb    = (const float*)d_in[1];
    const float* proj_w = (const float*)d_in[2];
    const float* proj_b = (const float*)d_in[3];
    const float* ln_g   = (const float*)d_in[4];
    const float* ln_b   = (const float*)d_in[5];
    const float* wq     = (const float*)d_in[6];
    const float* wk     = (const float*)d_in[7];
    const float* wv     = (const float*)d_in[8];
    const float* wo     = (const float*)d_in[9];
    const float* bq     = (const float*)d_in[10];
    const float* bk     = (const float*)d_in[11];
    const float* bv     = (const float*)d_in[12];
    const float* bo     = (const float*)d_in[13];
    const float* ffn_w1 = (const float*)d_in[14];
    const float* ffn_b1 = (const float*)d_in[15];
    const float* ffn_w2 = (const float*)d_in[16];
    const float* ffn_b2 = (const float*)d_in[17];
    const float* pw_w   = (const float*)d_in[18];
    const float* pw_b   = (const float*)d_in[19];

    unsigned short* X    = (unsigned short*)d_ws;        // bf16 residual stream
    unsigned short* Ho   = X + BUF;
    unsigned short* Qb   = Ho + BUF;
    unsigned short* Kb   = Qb + BUF;
    unsigned short* Vb   = Kb + BUF;
    unsigned short* Eg   = Vb + BUF;                     // NP*64
    unsigned short* wqkvb = Eg + (size_t)NP * 64;
    const int QKVSZ = NBLK * 2 * 576 * CCH;
    const int WSZ   = NBLK * 2 * CCH * CCH;
    const int FSZ   = NBLK * 768 * CCH;
    unsigned short* wob = wqkvb + QKVSZ;
    unsigned short* w1b = wob + WSZ;
    unsigned short* w2b = w1b + FSZ;
    unsigned short* pjb = w2b + FSZ;                     // 12288
    float* bqkvb = (float*)(pjb + 12288 + 32);
    float* Xt = (float*)Qb;                              // proj tmp fp32 (spans Qb+Kb, free pre-loop)

    wqkv_swz<<<QKVSZ / 256, 256, 0, stream>>>(wq, wk, wv, wqkvb);
    bqkv_concat<<<27, 256, 0, stream>>>(bq, bk, bv, bqkvb);
    swz_conv<192, 192><<<(WSZ + 255) / 256, 256, 0, stream>>>(wo, wob, NBLK * 2);
    swz_conv<768, 192><<<(FSZ + 255) / 256, 256, 0, stream>>>(ffn_w1, w1b, NBLK);
    swz_conv<192, 768><<<(FSZ + 255) / 256, 256, 0, stream>>>(ffn_w2, w2b, NBLK);
    swz_conv<192, 64><<<48, 256, 0, stream>>>(proj_w, pjb, 1);

    gather_kernel<<<NP * 64 / 256, 256, 0, stream>>>(tokens, emb, Eg);
    mm192<64, 1><<<dim3(1, NP / 64), 256, 0, stream>>>(Eg, pjb, proj_b,
                                                       nullptr, nullptr, nullptr, Xt, NP, CCH, 64);
    rotary_ln_kernel<<<NP / 4, 256, 0, stream>>>(Xt, X, Ho, ln_g, ln_b);
    mm192<128, 0><<<dim3(3, NP / 128), 256, 0, stream>>>(Ho, wqkvb, bqkvb,
                                                         Qb, Kb, Vb, nullptr, NP, 576, CCH);

    for (int i = 0; i < NBLK; ++i) {
        size_t wi0 = (size_t)(i * 2), wi1 = wi0 + 1;
        attn_axial<LL, 1><<<BB * SS, 256, 0, stream>>>(Qb, Kb, Vb, Ho);
        wo_qkv<<<NP / 64, 256, 0, stream>>>(Ho, wob + wi0 * CCH * CCH, bo + wi0 * CCH, X,
                                            ln_g + (size_t)(i * 3 + 1) * CCH, ln_b + (size_t)(i * 3 + 1) * CCH,
                                            wqkvb + wi1 * 576 * CCH, bqkvb + wi1 * 576, Qb, Kb, Vb);
        attn_axial<SS, LL><<<BB * LL, 256, 0, stream>>>(Qb, Kb, Vb, Ho);
        if (i < NBLK - 1) {
            size_t wn0 = (size_t)((i + 1) * 2);
            wo_ffn_qkv<false><<<NP / 64, 256, 0, stream>>>(
                Ho, wob + wi1 * CCH * CCH, bo + wi1 * CCH, X,
                ln_g + (size_t)(i * 3 + 2) * CCH, ln_b + (size_t)(i * 3 + 2) * CCH,
                w1b + (size_t)i * 768 * CCH, ffn_b1 + (size_t)i * 768,
                w2b + (size_t)i * CCH * 768, ffn_b2 + (size_t)i * CCH,
                ln_g + (size_t)((i + 1) * 3) * CCH, ln_b + (size_t)((i + 1) * 3) * CCH,
                wqkvb + wn0 * 576 * CCH, bqkvb + wn0 * 576, Qb, Kb, Vb);
        } else {
            wo_ffn_qkv<true><<<NP / 64, 256, 0, stream>>>(
                Ho, wob + wi1 * CCH * CCH, bo + wi1 * CCH, X,
                ln_g + (size_t)(i * 3 + 2) * CCH, ln_b + (size_t)(i * 3 + 2) * CCH,
                w1b + (size_t)i * 768 * CCH, ffn_b1 + (size_t)i * 768,
                w2b + (size_t)i * CCH * 768, ffn_b2 + (size_t)i * CCH,
                nullptr, nullptr, nullptr, nullptr, nullptr, nullptr, nullptr);
        }
    }
    final_kernel<<<NP / 4, 256, 0, stream>>>(X, pw_w, pw_b, (float*)d_out);
}

// Round 16
// 947.635 us; speedup vs baseline: 1.3070x; 1.1119x over previous
//
#include <hip/hip_runtime.h>
#include <hip/hip_bf16.h>
#include <math.h>

#define NBLK 6
#define NH 4
#define CCH 192
#define BB 2
#define SS 64
#define LL 256
#define DH 48
#define NP (BB*SS*LL)            // 32768 pixels
#define BUF ((size_t)NP*CCH)

typedef __attribute__((ext_vector_type(8))) short short8;
typedef __attribute__((ext_vector_type(4))) float float4v;

__device__ __forceinline__ unsigned short f2b(float f) {
    union { float f; unsigned int u; } v; v.f = f;
    unsigned int r = v.u + 0x7FFF + ((v.u >> 16) & 1);
    return (unsigned short)(r >> 16);
}
__device__ __forceinline__ float b2f(unsigned short u) {
    union { unsigned int u; float f; } v; v.u = ((unsigned int)u) << 16;
    return v.f;
}
__device__ __forceinline__ void async_lds16(const void* g, void* l) {
    __builtin_amdgcn_global_load_lds(
        (const __attribute__((address_space(1))) unsigned int*)g,
        (__attribute__((address_space(3))) unsigned int*)l, 16, 0, 0);
}

// ---------- weight prep: fragment-major swizzle ----------
template<int N, int K>
__global__ void swz_conv(const float* __restrict__ src, unsigned short* __restrict__ dst, int layers) {
    int s = blockIdx.x * 256 + threadIdx.x;
    if (s >= layers * N * K) return;
    int li = s / (N * K);
    int t = s - li * (N * K);
    constexpr int KC = K / 32;
    int chunk = t >> 9, c = t & 511;
    int g = chunk / KC, sk = chunk - g * KC;
    int lane = c >> 3, ko = c & 7;
    int n = g * 16 + (lane & 15), k = sk * 32 + (lane >> 4) * 8 + ko;
    dst[s] = f2b(src[(size_t)li * N * K + (size_t)n * K + k]);
}
__global__ void wqkv_swz(const float* __restrict__ wq, const float* __restrict__ wk,
                         const float* __restrict__ wv, unsigned short* __restrict__ d) {
    int s = blockIdx.x * 256 + threadIdx.x;          // 12*576*192
    int wi = s / (576 * 192);
    int t = s - wi * 576 * 192;
    int chunk = t >> 9, c = t & 511;
    int g = chunk / 6, sk = chunk - g * 6;
    int lane = c >> 3, ko = c & 7;
    int n = g * 16 + (lane & 15), k = sk * 32 + (lane >> 4) * 8 + ko;
    int sg = n / 192, row = n - sg * 192;
    const float* src = (sg == 0) ? wq : (sg == 1) ? wk : wv;
    d[s] = f2b(src[(size_t)wi * 192 * 192 + (size_t)row * 192 + k]);
}
__global__ void bqkv_concat(const float* __restrict__ bq, const float* __restrict__ bk,
                            const float* __restrict__ bv, float* __restrict__ d) {
    int idx = blockIdx.x * 256 + threadIdx.x;        // 12*576
    if (idx >= NBLK * 2 * 576) return;
    int wi = idx / 576, n = idx - (idx / 576) * 576;
    int sg = n / 192, row = n - sg * 192;
    const float* src = (sg == 0) ? bq : (sg == 1) ? bk : bv;
    d[idx] = src[wi * CCH + row];
}

__global__ void gather_kernel(const int* __restrict__ tokens, const float* __restrict__ emb,
                              unsigned short* __restrict__ Eg) {
    int idx = blockIdx.x * 256 + threadIdx.x;   // NP*64
    int p = idx >> 6, c = idx & 63;
    Eg[idx] = f2b(emb[tokens[p] * 64 + c]);
}

// rotary + first LayerNorm fused; X stored bf16 (storage only — math fp32)
__global__ __launch_bounds__(256) void rotary_ln_kernel(const float* __restrict__ Xt,
                                                        unsigned short* __restrict__ X,
                                                        unsigned short* __restrict__ Hn,
                                                        const float* __restrict__ g, const float* __restrict__ b) {
    int wave = threadIdx.x >> 6;
    int lane = threadIdx.x & 63;
    int p = blockIdx.x * 4 + wave;
    int l = p & (LL - 1);
    const float* xp = Xt + (size_t)p * CCH;
    float v[3];
    #pragma unroll
    for (int i = 0; i < 3; ++i) {
        int c = lane + i * 64;
        int j = c % 96;
        float inv = expf((float)(2 * j) * (-9.210340371976184f / 192.0f));
        float ang = (float)l * inv;
        float part = (c < 96) ? -xp[c + 96] : xp[c - 96];
        v[i] = xp[c] * cosf(ang) + part * sinf(ang);
    }
    float s = v[0] + v[1] + v[2];
    float qq = v[0] * v[0] + v[1] * v[1] + v[2] * v[2];
    #pragma unroll
    for (int off = 32; off; off >>= 1) {
        s += __shfl_xor(s, off, 64);
        qq += __shfl_xor(qq, off, 64);
    }
    float mean = s * (1.0f / 192.0f);
    float var = qq * (1.0f / 192.0f) - mean * mean;
    float r = rsqrtf(var + 1e-5f);
    unsigned short* op = X + (size_t)p * CCH;
    unsigned short* hp = Hn + (size_t)p * CCH;
    #pragma unroll
    for (int i = 0; i < 3; ++i) {
        int c = lane + i * 64;
        op[c] = f2b(v[i]);
        hp[c] = f2b((v[i] - mean) * r * g[c] + b[c]);
    }
}

// ---------------- bf16 MFMA GEMM (pre-loop only: proj, block-0 QKV) ----------------
template<int MT, int EPI>
__global__ __launch_bounds__(256, (MT == 128) ? 3 : 4)
void mm192(const unsigned short* __restrict__ A, const unsigned short* __restrict__ Wsw,
           const float* __restrict__ bias,
           unsigned short* __restrict__ O0, unsigned short* __restrict__ O1,
           unsigned short* __restrict__ O2,
           float* __restrict__ Of,
           int M, int N, int K) {
    constexpr int NI = MT / 32;
    __shared__ __align__(16) unsigned char lds[(MT == 128) ? 51200 : 28672];
    const int tid = threadIdx.x;
    const int lane = tid & 63;
    const int w = tid >> 6;
    const int wm = w >> 1, wn = w & 1;
    const int m0 = blockIdx.y * MT;
    const int g0 = blockIdx.x * 12;
    const int q = lane >> 4;
    const int q8 = q << 3;
    const int r15 = lane & 15;
    const int KC = K >> 5;

    for (int c = w; c < (MT / 16) * KC; c += 4) {
        int g = c / KC, sk = c - g * KC;
        async_lds16(A + (size_t)(m0 + g * 16 + r15) * K + sk * 32 + q8, lds + c * 1024);
    }

    float4v acc[NI][6];
    #pragma unroll
    for (int i = 0; i < NI; ++i)
        #pragma unroll
        for (int j = 0; j < 6; ++j)
            acc[i][j] = (float4v){0.f, 0.f, 0.f, 0.f};

    __syncthreads();

    for (int sk = 0; sk < KC; ++sk) {
        short8 af[NI], wf[6];
        #pragma unroll
        for (int j = 0; j < 6; ++j)
            wf[j] = *(const short8*)(Wsw + (((size_t)(g0 + wn * 6 + j) * KC + sk) << 9) + lane * 8);
        #pragma unroll
        for (int i = 0; i < NI; ++i)
            af[i] = *(const short8*)(lds + (((wm * NI + i) * KC + sk) << 10) + lane * 16);
        #pragma unroll
        for (int i = 0; i < NI; ++i)
            #pragma unroll
            for (int j = 0; j < 6; ++j)
                acc[i][j] = __builtin_amdgcn_mfma_f32_16x16x32_bf16(af[i], wf[j], acc[i][j], 0, 0, 0);
    }

    const int nb = blockIdx.x * 192 + wn * 96 + r15;
    const int mb = m0 + wm * (MT / 2) + q * 4;

    if (EPI == 0) {
        unsigned short* TB = (unsigned short*)lds;
        const int bx = blockIdx.x;
        __syncthreads();
        #pragma unroll
        for (int j = 0; j < 6; ++j) {
            float bv = bias[nb + j * 16];
            #pragma unroll
            for (int i = 0; i < NI; ++i) {
                int row = wm * (MT / 2) + i * 16 + q * 4;
                #pragma unroll
                for (int r = 0; r < 4; ++r) {
                    float v = acc[i][j][r] + bv;
                    if (bx < 2) v = (v > 0.f) ? v + 1.f : expf(v);
                    if (bx == 0) v *= 0.14433756729740643f;
                    TB[(row + r) * 200 + wn * 96 + j * 16 + r15] = f2b(v);
                }
            }
        }
        __syncthreads();
        unsigned short* dst = (bx == 0) ? O0 : (bx == 1) ? O1 : O2;
        #pragma unroll
        for (int it = 0; it < (MT * 192) / 2048; ++it) {
            int idx = (it * 256 + tid) * 8;
            int row = idx / 192, col = idx - row * 192;
            *(short8*)(dst + (size_t)(m0 + row) * 192 + col) = *(const short8*)&TB[row * 200 + col];
        }
    } else {
        #pragma unroll
        for (int j = 0; j < 6; ++j) {
            int n = nb + j * 16;
            float bv = bias[n];
            #pragma unroll
            for (int i = 0; i < NI; ++i) {
                int mrow = mb + i * 16;
                #pragma unroll
                for (int r = 0; r < 4; ++r)
                    Of[(size_t)(mrow + r) * N + n] = acc[i][j][r] + bv;
            }
        }
    }
}

// ======== fused per-pixel GEMM chains: 64 rows/block, 512 threads (8 waves) ========
// Wave (wm = w>>2 in {0,1}, wn = w&3 in {0..3}) owns 32 rows x 48 cols.
// LDS (52224 B): Lo [0,25600) staging/Hreg/TB | stats [25600,27648) [64][4]x2 | Ap [27648,52224)
// A'/Hreg chunk layout: chunk (g*6+sk)*1024B, element (m=g*16+r15, k=sk*32+q*8+t).

// ---- WO + residual + LN + QKV ----
__global__ __launch_bounds__(512, 4)
void wo_qkv(const unsigned short* __restrict__ Ho,
            const unsigned short* __restrict__ WOs, const float* __restrict__ BO,
            unsigned short* __restrict__ Xres,
            const float* __restrict__ lng, const float* __restrict__ lnb,
            const unsigned short* __restrict__ QKVs, const float* __restrict__ bqkv,
            unsigned short* __restrict__ Qb, unsigned short* __restrict__ Kb,
            unsigned short* __restrict__ Vb) {
    __shared__ __align__(16) unsigned char lds[52224];
    unsigned char* Lo = lds;
    float* lsum = (float*)(lds + 25600);     // [64][4]
    float* lsq  = lsum + 256;
    unsigned char* Ap = lds + 27648;
    const int tid = threadIdx.x;
    const int lane = tid & 63;
    const int w = tid >> 6;                  // 0..7
    const int wm = w >> 2, wn = w & 3;
    const int m0 = blockIdx.x * 64;
    const int q = lane >> 4, q8 = q << 3, r15 = lane & 15;
    const int nb = wn * 48 + r15;

    #pragma unroll
    for (int it = 0; it < 3; ++it) {
        int c = it * 8 + w;
        int g = c / 6, sk = c - (c / 6) * 6;
        async_lds16(Ho + (size_t)(m0 + g * 16 + r15) * 192 + sk * 32 + q8, Lo + c * 1024);
    }
    __syncthreads();

    float4v acc[2][3];
    #pragma unroll
    for (int i = 0; i < 2; ++i)
        #pragma unroll
        for (int j = 0; j < 3; ++j)
            acc[i][j] = (float4v){0.f, 0.f, 0.f, 0.f};
    #pragma unroll
    for (int kk = 0; kk < 6; ++kk) {
        short8 af[2], wf[3];
        #pragma unroll
        for (int j = 0; j < 3; ++j)
            wf[j] = *(const short8*)(WOs + (((size_t)(wn * 3 + j) * 6 + kk) << 9) + lane * 8);
        #pragma unroll
        for (int i = 0; i < 2; ++i)
            af[i] = *(const short8*)(Lo + (((wm * 2 + i) * 6 + kk) << 10) + lane * 16);
        #pragma unroll
        for (int i = 0; i < 2; ++i)
            #pragma unroll
            for (int j = 0; j < 3; ++j)
                acc[i][j] = __builtin_amdgcn_mfma_f32_16x16x32_bf16(af[i], wf[j], acc[i][j], 0, 0, 0);
    }

    // residual, X write (bf16), LN stats
    #pragma unroll
    for (int j = 0; j < 3; ++j) {
        int n = nb + j * 16;
        float bv = BO[n];
        #pragma unroll
        for (int i = 0; i < 2; ++i) {
            int mrow = m0 + wm * 32 + i * 16 + q * 4;
            #pragma unroll
            for (int r = 0; r < 4; ++r) {
                acc[i][j][r] += bv + b2f(Xres[(size_t)(mrow + r) * 192 + n]);
                Xres[(size_t)(mrow + r) * 192 + n] = f2b(acc[i][j][r]);
            }
        }
    }
    #pragma unroll
    for (int i = 0; i < 2; ++i)
        #pragma unroll
        for (int r = 0; r < 4; ++r) {
            float s1 = 0.f, s2 = 0.f;
            #pragma unroll
            for (int j = 0; j < 3; ++j) { float v = acc[i][j][r]; s1 += v; s2 += v * v; }
            #pragma unroll
            for (int off = 1; off < 16; off <<= 1) {
                s1 += __shfl_xor(s1, off, 64);
                s2 += __shfl_xor(s2, off, 64);
            }
            if (r15 == 0) {
                int rl = wm * 32 + i * 16 + q * 4 + r;
                lsum[rl * 4 + wn] = s1;
                lsq[rl * 4 + wn] = s2;
            }
        }
    __syncthreads();
    #pragma unroll
    for (int i = 0; i < 2; ++i) {
        int g = wm * 2 + i;
        #pragma unroll
        for (int r = 0; r < 4; ++r) {
            int rl = g * 16 + q * 4 + r;
            float mean = (lsum[rl * 4] + lsum[rl * 4 + 1] + lsum[rl * 4 + 2] + lsum[rl * 4 + 3]) * (1.0f / 192.0f);
            float var = (lsq[rl * 4] + lsq[rl * 4 + 1] + lsq[rl * 4 + 2] + lsq[rl * 4 + 3]) * (1.0f / 192.0f)
                      - mean * mean;
            float rstd = rsqrtf(var + 1e-5f);
            #pragma unroll
            for (int j = 0; j < 3; ++j) {
                int h = nb + j * 16;
                int base = (g * 6 + (h >> 5)) * 512 + ((h >> 3) & 3) * 128 + (h & 7);
                float v = (acc[i][j][r] - mean) * rstd * lng[h] + lnb[h];
                ((unsigned short*)Ap)[base + (q * 4 + r) * 8] = f2b(v);
            }
        }
    }
    __syncthreads();

    // QKV: 3 segments
    unsigned short* TB = (unsigned short*)Lo;
    for (int seg = 0; seg < 3; ++seg) {
        float4v a2[2][3];
        #pragma unroll
        for (int i = 0; i < 2; ++i)
            #pragma unroll
            for (int j = 0; j < 3; ++j)
                a2[i][j] = (float4v){0.f, 0.f, 0.f, 0.f};
        #pragma unroll
        for (int kk = 0; kk < 6; ++kk) {
            short8 af[2], wf[3];
            #pragma unroll
            for (int j = 0; j < 3; ++j)
                wf[j] = *(const short8*)(QKVs + (((size_t)(seg * 12 + wn * 3 + j) * 6 + kk) << 9) + lane * 8);
            #pragma unroll
            for (int i = 0; i < 2; ++i)
                af[i] = *(const short8*)(Ap + (((wm * 2 + i) * 6 + kk) << 10) + lane * 16);
            #pragma unroll
            for (int i = 0; i < 2; ++i)
                #pragma unroll
                for (int j = 0; j < 3; ++j)
                    a2[i][j] = __builtin_amdgcn_mfma_f32_16x16x32_bf16(af[i], wf[j], a2[i][j], 0, 0, 0);
        }
        __syncthreads();
        #pragma unroll
        for (int j = 0; j < 3; ++j) {
            float bv = bqkv[seg * 192 + nb + j * 16];
            #pragma unroll
            for (int i = 0; i < 2; ++i) {
                int row = wm * 32 + i * 16 + q * 4;
                #pragma unroll
                for (int r = 0; r < 4; ++r) {
                    float v = a2[i][j][r] + bv;
                    if (seg < 2) v = (v > 0.f) ? v + 1.f : expf(v);
                    if (seg == 0) v *= 0.14433756729740643f;
                    TB[(row + r) * 200 + nb + j * 16] = f2b(v);
                }
            }
        }
        __syncthreads();
        unsigned short* dst = (seg == 0) ? Qb : (seg == 1) ? Kb : Vb;
        #pragma unroll
        for (int it = 0; it < 3; ++it) {
            int idx = (it * 512 + tid) * 8;
            int row = idx / 192, col = idx - row * 192;
            *(short8*)(dst + (size_t)(m0 + row) * 192 + col) = *(const short8*)&TB[row * 200 + col];
        }
    }
}

// ---- WO + residual(reg) + LN + FFN + residual + LN + next-QKV ----
template<bool LASTB>
__global__ __launch_bounds__(512, 4)
void wo_ffn_qkv(const unsigned short* __restrict__ Ho,
                const unsigned short* __restrict__ WOs, const float* __restrict__ BO,
                unsigned short* __restrict__ Xres,
                const float* __restrict__ ln1g, const float* __restrict__ ln1b,
                const unsigned short* __restrict__ W1s, const float* __restrict__ B1,
                const unsigned short* __restrict__ W2s, const float* __restrict__ B2,
                const float* __restrict__ ln2g, const float* __restrict__ ln2b,
                const unsigned short* __restrict__ QKVs, const float* __restrict__ bqkv,
                unsigned short* __restrict__ Qb, unsigned short* __restrict__ Kb,
                unsigned short* __restrict__ Vb) {
    __shared__ __align__(16) unsigned char lds[52224];
    unsigned char* Lo = lds;
    float* lsum = (float*)(lds + 25600);     // [64][4]
    float* lsq  = lsum + 256;
    unsigned char* Ap = lds + 27648;
    const int tid = threadIdx.x;
    const int lane = tid & 63;
    const int w = tid >> 6;                  // 0..7
    const int wm = w >> 2, wn = w & 3;
    const int m0 = blockIdx.x * 64;
    const int q = lane >> 4, q8 = q << 3, r15 = lane & 15;
    const int nb = wn * 48 + r15;

    #pragma unroll
    for (int it = 0; it < 3; ++it) {
        int c = it * 8 + w;
        int g = c / 6, sk = c - (c / 6) * 6;
        async_lds16(Ho + (size_t)(m0 + g * 16 + r15) * 192 + sk * 32 + q8, Lo + c * 1024);
    }
    __syncthreads();

    float4v xres[2][3];
    #pragma unroll
    for (int i = 0; i < 2; ++i)
        #pragma unroll
        for (int j = 0; j < 3; ++j)
            xres[i][j] = (float4v){0.f, 0.f, 0.f, 0.f};
    #pragma unroll
    for (int kk = 0; kk < 6; ++kk) {
        short8 af[2], wf[3];
        #pragma unroll
        for (int j = 0; j < 3; ++j)
            wf[j] = *(const short8*)(WOs + (((size_t)(wn * 3 + j) * 6 + kk) << 9) + lane * 8);
        #pragma unroll
        for (int i = 0; i < 2; ++i)
            af[i] = *(const short8*)(Lo + (((wm * 2 + i) * 6 + kk) << 10) + lane * 16);
        #pragma unroll
        for (int i = 0; i < 2; ++i)
            #pragma unroll
            for (int j = 0; j < 3; ++j)
                xres[i][j] = __builtin_amdgcn_mfma_f32_16x16x32_bf16(af[i], wf[j], xres[i][j], 0, 0, 0);
    }
    // residual into registers (X read once; write deferred)
    #pragma unroll
    for (int j = 0; j < 3; ++j) {
        int n = nb + j * 16;
        float bv = BO[n];
        #pragma unroll
        for (int i = 0; i < 2; ++i) {
            int mrow = m0 + wm * 32 + i * 16 + q * 4;
            #pragma unroll
            for (int r = 0; r < 4; ++r)
                xres[i][j][r] += bv + b2f(Xres[(size_t)(mrow + r) * 192 + n]);
        }
    }
    // LN1 stats + scatter A'
    #pragma unroll
    for (int i = 0; i < 2; ++i)
        #pragma unroll
        for (int r = 0; r < 4; ++r) {
            float s1 = 0.f, s2 = 0.f;
            #pragma unroll
            for (int j = 0; j < 3; ++j) { float v = xres[i][j][r]; s1 += v; s2 += v * v; }
            #pragma unroll
            for (int off = 1; off < 16; off <<= 1) {
                s1 += __shfl_xor(s1, off, 64);
                s2 += __shfl_xor(s2, off, 64);
            }
            if (r15 == 0) {
                int rl = wm * 32 + i * 16 + q * 4 + r;
                lsum[rl * 4 + wn] = s1;
                lsq[rl * 4 + wn] = s2;
            }
        }
    __syncthreads();
    #pragma unroll
    for (int i = 0; i < 2; ++i) {
        int g = wm * 2 + i;
        #pragma unroll
        for (int r = 0; r < 4; ++r) {
            int rl = g * 16 + q * 4 + r;
            float mean = (lsum[rl * 4] + lsum[rl * 4 + 1] + lsum[rl * 4 + 2] + lsum[rl * 4 + 3]) * (1.0f / 192.0f);
            float var = (lsq[rl * 4] + lsq[rl * 4 + 1] + lsq[rl * 4 + 2] + lsq[rl * 4 + 3]) * (1.0f / 192.0f)
                      - mean * mean;
            float rstd = rsqrtf(var + 1e-5f);
            #pragma unroll
            for (int j = 0; j < 3; ++j) {
                int h = nb + j * 16;
                int base = (g * 6 + (h >> 5)) * 512 + ((h >> 3) & 3) * 128 + (h & 7);
                float v = (xres[i][j][r] - mean) * rstd * ln1g[h] + ln1b[h];
                ((unsigned short*)Ap)[base + (q * 4 + r) * 8] = f2b(v);
            }
        }
    }
    __syncthreads();

    // FFN: hidden chunks of 192, hidden lives only in LDS (Lo)
    float4v acc2[2][3];
    #pragma unroll
    for (int i = 0; i < 2; ++i)
        #pragma unroll
        for (int j = 0; j < 3; ++j)
            acc2[i][j] = (float4v){0.f, 0.f, 0.f, 0.f};
    for (int hc = 0; hc < 4; ++hc) {
        float4v acc1[2][3];
        #pragma unroll
        for (int i = 0; i < 2; ++i)
            #pragma unroll
            for (int j = 0; j < 3; ++j)
                acc1[i][j] = (float4v){0.f, 0.f, 0.f, 0.f};
        #pragma unroll
        for (int kk = 0; kk < 6; ++kk) {
            short8 af[2], wf[3];
            #pragma unroll
            for (int j = 0; j < 3; ++j)
                wf[j] = *(const short8*)(W1s + (((size_t)(hc * 12 + wn * 3 + j) * 6 + kk) << 9) + lane * 8);
            #pragma unroll
            for (int i = 0; i < 2; ++i)
                af[i] = *(const short8*)(Ap + (((wm * 2 + i) * 6 + kk) << 10) + lane * 16);
            #pragma unroll
            for (int i = 0; i < 2; ++i)
                #pragma unroll
                for (int j = 0; j < 3; ++j)
                    acc1[i][j] = __builtin_amdgcn_mfma_f32_16x16x32_bf16(af[i], wf[j], acc1[i][j], 0, 0, 0);
        }
        __syncthreads();
        #pragma unroll
        for (int i = 0; i < 2; ++i) {
            int g = wm * 2 + i;
            #pragma unroll
            for (int j = 0; j < 3; ++j) {
                int h = nb + j * 16;
                float bv = B1[hc * 192 + h];
                int base = (g * 6 + (h >> 5)) * 512 + ((h >> 3) & 3) * 128 + (h & 7);
                #pragma unroll
                for (int r = 0; r < 4; ++r) {
                    float v = acc1[i][j][r] + bv;
                    v = 0.5f * v * (1.0f + erff(v * 0.7071067811865475f));
                    ((unsigned short*)Lo)[base + (q * 4 + r) * 8] = f2b(v);
                }
            }
        }
        __syncthreads();
        #pragma unroll
        for (int kk = 0; kk < 6; ++kk) {
            short8 af[2], wf[3];
            #pragma unroll
            for (int j = 0; j < 3; ++j)
                wf[j] = *(const short8*)(W2s + (((size_t)(wn * 3 + j) * 24 + hc * 6 + kk) << 9) + lane * 8);
            #pragma unroll
            for (int i = 0; i < 2; ++i)
                af[i] = *(const short8*)(Lo + (((wm * 2 + i) * 6 + kk) << 10) + lane * 16);
            #pragma unroll
            for (int i = 0; i < 2; ++i)
                #pragma unroll
                for (int j = 0; j < 3; ++j)
                    acc2[i][j] = __builtin_amdgcn_mfma_f32_16x16x32_bf16(af[i], wf[j], acc2[i][j], 0, 0, 0);
        }
    }

    // FFN residual; single X write (bf16)
    #pragma unroll
    for (int j = 0; j < 3; ++j) {
        int n = nb + j * 16;
        float bv = B2[n];
        #pragma unroll
        for (int i = 0; i < 2; ++i) {
            int mrow = m0 + wm * 32 + i * 16 + q * 4;
            #pragma unroll
            for (int r = 0; r < 4; ++r) {
                xres[i][j][r] += acc2[i][j][r] + bv;
                Xres[(size_t)(mrow + r) * 192 + n] = f2b(xres[i][j][r]);
            }
        }
    }
    if (LASTB) return;

    // LN2 + next-block QKV
    #pragma unroll
    for (int i = 0; i < 2; ++i)
        #pragma unroll
        for (int r = 0; r < 4; ++r) {
            float s1 = 0.f, s2 = 0.f;
            #pragma unroll
            for (int j = 0; j < 3; ++j) { float v = xres[i][j][r]; s1 += v; s2 += v * v; }
            #pragma unroll
            for (int off = 1; off < 16; off <<= 1) {
                s1 += __shfl_xor(s1, off, 64);
                s2 += __shfl_xor(s2, off, 64);
            }
            if (r15 == 0) {
                int rl = wm * 32 + i * 16 + q * 4 + r;
                lsum[rl * 4 + wn] = s1;
                lsq[rl * 4 + wn] = s2;
            }
        }
    __syncthreads();
    #pragma unroll
    for (int i = 0; i < 2; ++i) {
        int g = wm * 2 + i;
        #pragma unroll
        for (int r = 0; r < 4; ++r) {
            int rl = g * 16 + q * 4 + r;
            float mean = (lsum[rl * 4] + lsum[rl * 4 + 1] + lsum[rl * 4 + 2] + lsum[rl * 4 + 3]) * (1.0f / 192.0f);
            float var = (lsq[rl * 4] + lsq[rl * 4 + 1] + lsq[rl * 4 + 2] + lsq[rl * 4 + 3]) * (1.0f / 192.0f)
                      - mean * mean;
            float rstd = rsqrtf(var + 1e-5f);
            #pragma unroll
            for (int j = 0; j < 3; ++j) {
                int h = nb + j * 16;
                int base = (g * 6 + (h >> 5)) * 512 + ((h >> 3) & 3) * 128 + (h & 7);
                float v = (xres[i][j][r] - mean) * rstd * ln2g[h] + ln2b[h];
                ((unsigned short*)Ap)[base + (q * 4 + r) * 8] = f2b(v);
            }
        }
    }
    __syncthreads();

    unsigned short* TB = (unsigned short*)Lo;
    for (int seg = 0; seg < 3; ++seg) {
        float4v a2[2][3];
        #pragma unroll
        for (int i = 0; i < 2; ++i)
            #pragma unroll
            for (int j = 0; j < 3; ++j)
                a2[i][j] = (float4v){0.f, 0.f, 0.f, 0.f};
        #pragma unroll
        for (int kk = 0; kk < 6; ++kk) {
            short8 af[2], wf[3];
            #pragma unroll
            for (int j = 0; j < 3; ++j)
                wf[j] = *(const short8*)(QKVs + (((size_t)(seg * 12 + wn * 3 + j) * 6 + kk) << 9) + lane * 8);
            #pragma unroll
            for (int i = 0; i < 2; ++i)
                af[i] = *(const short8*)(Ap + (((wm * 2 + i) * 6 + kk) << 10) + lane * 16);
            #pragma unroll
            for (int i = 0; i < 2; ++i)
                #pragma unroll
                for (int j = 0; j < 3; ++j)
                    a2[i][j] = __builtin_amdgcn_mfma_f32_16x16x32_bf16(af[i], wf[j], a2[i][j], 0, 0, 0);
        }
        __syncthreads();
        #pragma unroll
        for (int j = 0; j < 3; ++j) {
            float bv = bqkv[seg * 192 + nb + j * 16];
            #pragma unroll
            for (int i = 0; i < 2; ++i) {
                int row = wm * 32 + i * 16 + q * 4;
                #pragma unroll
                for (int r = 0; r < 4; ++r) {
                    float v = a2[i][j][r] + bv;
                    if (seg < 2) v = (v > 0.f) ? v + 1.f : expf(v);
                    if (seg == 0) v *= 0.14433756729740643f;
                    TB[(row + r) * 200 + nb + j * 16] = f2b(v);
                }
            }
        }
        __syncthreads();
        unsigned short* dst = (seg == 0) ? Qb : (seg == 1) ? Kb : Vb;
        #pragma unroll
        for (int it = 0; it < 3; ++it) {
            int idx = (it * 512 + tid) * 8;
            int row = idx / 192, col = idx - row * 192;
            *(short8*)(dst + (size_t)(m0 + row) * 192 + col) = *(const short8*)&TB[row * 200 + col];
        }
    }
}

// ---------------- axial linear attention (separate Q/K/V [m][192] buffers) ----------------
template<int N, int MSTR>
__global__ __launch_bounds__(256) void attn_axial(const unsigned short* __restrict__ Qb,
                                                  const unsigned short* __restrict__ Kb,
                                                  const unsigned short* __restrict__ Vb,
                                                  unsigned short* __restrict__ O) {
    __shared__ unsigned short KV[32][400];
    __shared__ unsigned short kvs[4][64][72];
    const int tid = threadIdx.x;
    const int lane = tid & 63;
    const int w = tid >> 6;
    const int q = lane >> 4, r15 = lane & 15, q8 = q * 8;
    size_t base;
    if (MSTR == 1) base = (size_t)blockIdx.x * N;
    else           base = (size_t)(blockIdx.x >> 8) * 16384 + (blockIdx.x & 255);

    unsigned int* kz = (unsigned int*)&kvs[w][0][0];
    #pragma unroll
    for (int ii = 0; ii < 36; ++ii) kz[lane + ii * 64] = 0;

    short8 onesf;
    #pragma unroll
    for (int e = 0; e < 8; ++e) onesf[e] = (short)0x3F80;

    float4v kv[3][4];
    #pragma unroll
    for (int i = 0; i < 3; ++i)
        #pragma unroll
        for (int j = 0; j < 4; ++j)
            kv[i][j] = (float4v){0.f, 0.f, 0.f, 0.f};

    for (int ks = 0; ks < N; ks += 32) {
        #pragma unroll
        for (int it = 0; it < 6; ++it) {
            int cc = tid + it * 256;
            int row = cc / 48, c8 = cc - (cc / 48) * 48;
            size_t poff = (base + (size_t)(ks + row) * MSTR) * 192;
            const unsigned short* gp = (c8 < 24) ? (Kb + poff + c8 * 8) : (Vb + poff + (c8 - 24) * 8);
            *(short8*)&KV[row][c8 * 8] = *(const short8*)gp;
        }
        __syncthreads();
        short8 af[3], bf[3];
        #pragma unroll
        for (int t = 0; t < 3; ++t) {
            #pragma unroll
            for (int j = 0; j < 8; ++j) {
                af[t][j] = (short)KV[q8 + j][w * 48 + t * 16 + r15];
                bf[t][j] = (short)KV[q8 + j][192 + w * 48 + t * 16 + r15];
            }
        }
        #pragma unroll
        for (int i = 0; i < 3; ++i) {
            #pragma unroll
            for (int j = 0; j < 3; ++j)
                kv[i][j] = __builtin_amdgcn_mfma_f32_16x16x32_bf16(af[i], bf[j], kv[i][j], 0, 0, 0);
            kv[i][3] = __builtin_amdgcn_mfma_f32_16x16x32_bf16(af[i], onesf, kv[i][3], 0, 0, 0);
        }
        __syncthreads();
    }

    #pragma unroll
    for (int i = 0; i < 3; ++i) {
        #pragma unroll
        for (int j = 0; j < 3; ++j)
            #pragma unroll
            for (int r = 0; r < 4; ++r)
                kvs[w][j * 16 + r15][i * 16 + q * 4 + r] = f2b(kv[i][j][r]);
        if (r15 == 0)
            #pragma unroll
            for (int r = 0; r < 4; ++r)
                kvs[w][48][i * 16 + q * 4 + r] = f2b(kv[i][3][r]);
    }

    short8 bkv[2][4];
    #pragma unroll
    for (int kk = 0; kk < 2; ++kk)
        #pragma unroll
        for (int t = 0; t < 4; ++t)
            bkv[kk][t] = *(const short8*)&kvs[w][t * 16 + r15][kk * 32 + q8];

    for (int mt = 0; mt < N / 16; ++mt) {
        float4v o[4];
        #pragma unroll
        for (int t = 0; t < 4; ++t) o[t] = (float4v){0.f, 0.f, 0.f, 0.f};
        #pragma unroll
        for (int kk = 0; kk < 2; ++kk) {
            const unsigned short* qp = Qb + (base + (size_t)(mt * 16 + r15) * MSTR) * 192
                                       + w * 48 + kk * 32 + q8;
            short8 aq = *(const short8*)qp;
            #pragma unroll
            for (int t = 0; t < 4; ++t)
                o[t] = __builtin_amdgcn_mfma_f32_16x16x32_bf16(aq, bkv[kk][t], o[t], 0, 0, 0);
        }
        #pragma unroll
        for (int r = 0; r < 4; ++r) {
            float den = __shfl(o[3][r], q << 4);
            float z = 1.0f / (den + 1e-6f);
            int n = mt * 16 + q * 4 + r;
            unsigned short* op = O + (base + (size_t)n * MSTR) * 192 + w * 48;
            #pragma unroll
            for (int t = 0; t < 3; ++t)
                op[t * 16 + r15] = f2b(o[t][r] * z);
        }
    }
}

__global__ __launch_bounds__(256) void final_kernel(const unsigned short* __restrict__ X,
                                                    const float* __restrict__ pw_w,
                                                    const float* __restrict__ pw_b, float* __restrict__ out) {
    int wave = threadIdx.x >> 6;
    int lane = threadIdx.x & 63;
    int p = blockIdx.x * 4 + wave;
    const unsigned short* xp = X + (size_t)p * CCH;
    float s = b2f(xp[lane]) * pw_w[lane] + b2f(xp[lane + 64]) * pw_w[lane + 64]
            + b2f(xp[lane + 128]) * pw_w[lane + 128];
    #pragma unroll
    for (int off = 32; off; off >>= 1) s += __shfl_xor(s, off, 64);
    if (lane == 0) {
        float o = s + pw_b[0];
        float e = expf(o);
        out[p] = 1.0f - 1.0f / (2.0f + e);
    }
}

extern "C" void kernel_launch(void* const* d_in, const int* in_sizes, int n_in,
                              void* d_out, int out_size, void* d_ws, size_t ws_size,
                              hipStream_t stream) {
    const int*   tokens = (const int*)  d_in[0];
    const float* emb    = (const float*)d_in[1];
    const float* proj_w = (const float*)d_in[2];
    const float* proj_b = (const float*)d_in[3];
    const float* ln_g   = (const float*)d_in[4];
    const float* ln_b   = (const float*)d_in[5];
    const float* wq     = (const float*)d_in[6];
    const float* wk     = (const float*)d_in[7];
    const float* wv     = (const float*)d_in[8];
    const float* wo     = (const float*)d_in[9];
    const float* bq     = (const float*)d_in[10];
    const float* bk     = (const float*)d_in[11];
    const float* bv     = (const float*)d_in[12];
    const float* bo     = (const float*)d_in[13];
    const float* ffn_w1 = (const float*)d_in[14];
    const float* ffn_b1 = (const float*)d_in[15];
    const float* ffn_w2 = (const float*)d_in[16];
    const float* ffn_b2 = (const float*)d_in[17];
    const float* pw_w   = (const float*)d_in[18];
    const float* pw_b   = (const float*)d_in[19];

    unsigned short* X    = (unsigned short*)d_ws;        // bf16 residual stream
    unsigned short* Ho   = X + BUF;
    unsigned short* Qb   = Ho + BUF;
    unsigned short* Kb   = Qb + BUF;
    unsigned short* Vb   = Kb + BUF;
    unsigned short* Eg   = Vb + BUF;                     // NP*64
    unsigned short* wqkvb = Eg + (size_t)NP * 64;
    const int QKVSZ = NBLK * 2 * 576 * CCH;
    const int WSZ   = NBLK * 2 * CCH * CCH;
    const int FSZ   = NBLK * 768 * CCH;
    unsigned short* wob = wqkvb + QKVSZ;
    unsigned short* w1b = wob + WSZ;
    unsigned short* w2b = w1b + FSZ;
    unsigned short* pjb = w2b + FSZ;                     // 12288
    float* bqkvb = (float*)(pjb + 12288 + 32);
    float* Xt = (float*)Qb;                              // proj tmp fp32 (spans Qb+Kb, free pre-loop)

    wqkv_swz<<<QKVSZ / 256, 256, 0, stream>>>(wq, wk, wv, wqkvb);
    bqkv_concat<<<27, 256, 0, stream>>>(bq, bk, bv, bqkvb);
    swz_conv<192, 192><<<(WSZ + 255) / 256, 256, 0, stream>>>(wo, wob, NBLK * 2);
    swz_conv<768, 192><<<(FSZ + 255) / 256, 256, 0, stream>>>(ffn_w1, w1b, NBLK);
    swz_conv<192, 768><<<(FSZ + 255) / 256, 256, 0, stream>>>(ffn_w2, w2b, NBLK);
    swz_conv<192, 64><<<48, 256, 0, stream>>>(proj_w, pjb, 1);

    gather_kernel<<<NP * 64 / 256, 256, 0, stream>>>(tokens, emb, Eg);
    mm192<64, 1><<<dim3(1, NP / 64), 256, 0, stream>>>(Eg, pjb, proj_b,
                                                       nullptr, nullptr, nullptr, Xt, NP, CCH, 64);
    rotary_ln_kernel<<<NP / 4, 256, 0, stream>>>(Xt, X, Ho, ln_g, ln_b);
    mm192<128, 0><<<dim3(3, NP / 128), 256, 0, stream>>>(Ho, wqkvb, bqkvb,
                                                         Qb, Kb, Vb, nullptr, NP, 576, CCH);

    for (int i = 0; i < NBLK; ++i) {
        size_t wi0 = (size_t)(i * 2), wi1 = wi0 + 1;
        attn_axial<LL, 1><<<BB * SS, 256, 0, stream>>>(Qb, Kb, Vb, Ho);
        wo_qkv<<<NP / 64, 512, 0, stream>>>(Ho, wob + wi0 * CCH * CCH, bo + wi0 * CCH, X,
                                            ln_g + (size_t)(i * 3 + 1) * CCH, ln_b + (size_t)(i * 3 + 1) * CCH,
                                            wqkvb + wi1 * 576 * CCH, bqkvb + wi1 * 576, Qb, Kb, Vb);
        attn_axial<SS, LL><<<BB * LL, 256, 0, stream>>>(Qb, Kb, Vb, Ho);
        if (i < NBLK - 1) {
            size_t wn0 = (size_t)((i + 1) * 2);
            wo_ffn_qkv<false><<<NP / 64, 512, 0, stream>>>(
                Ho, wob + wi1 * CCH * CCH, bo + wi1 * CCH, X,
                ln_g + (size_t)(i * 3 + 2) * CCH, ln_b + (size_t)(i * 3 + 2) * CCH,
                w1b + (size_t)i * 768 * CCH, ffn_b1 + (size_t)i * 768,
                w2b + (size_t)i * CCH * 768, ffn_b2 + (size_t)i * CCH,
                ln_g + (size_t)((i + 1) * 3) * CCH, ln_b + (size_t)((i + 1) * 3) * CCH,
                wqkvb + wn0 * 576 * CCH, bqkvb + wn0 * 576, Qb, Kb, Vb);
        } else {
            wo_ffn_qkv<true><<<NP / 64, 512, 0, stream>>>(
                Ho, wob + wi1 * CCH * CCH, bo + wi1 * CCH, X,
                ln_g + (size_t)(i * 3 + 2) * CCH, ln_b + (size_t)(i * 3 + 2) * CCH,
                w1b + (size_t)i * 768 * CCH, ffn_b1 + (size_t)i * 768,
                w2b + (size_t)i * CCH * 768, ffn_b2 + (size_t)i * CCH,
                nullptr, nullptr, nullptr, nullptr, nullptr, nullptr, nullptr);
        }
    }
    final_kernel<<<NP / 4, 256, 0, stream>>>(X, pw_w, pw_b, (float*)d_out);
}